// Round 1
// baseline (5699.792 us; speedup 1.0000x reference)
//
#include <hip/hip_runtime.h>

#define NN 100000
#define NE 1600000

// ---------------------------------------------------------------------------
// Edge kernel: one thread per edge.
//   x = [h[dst](64) , h[src](64)],  h = [pos(32), vel(32)]
//   y = relu(x @ w1 + b1)   (w1: [128,64])
//   m = y @ w2 + b2          (w2: [64,64])
//   atomicAdd(aggr[dst], m)
// Weight reads are wave-uniform -> scalar loads (SGPR operands on v_fma).
// ---------------------------------------------------------------------------
extern "C" __global__ void __launch_bounds__(256)
edge_msg_kernel(const float* __restrict__ pos,
                const float* __restrict__ vel,
                const int*   __restrict__ ei,
                const float* __restrict__ w1,
                const float* __restrict__ b1,
                const float* __restrict__ w2,
                const float* __restrict__ b2,
                float* __restrict__ aggr)
{
    const int e = blockIdx.x * 256 + threadIdx.x;
    if (e >= NE) return;
    const int ns = ei[e];        // src
    const int nd = ei[NE + e];   // dst

    float y[64];
#pragma unroll
    for (int j = 0; j < 64; ++j) y[j] = b1[j];

    // layer 1: 4 parts of 32 inputs: pos[nd], vel[nd], pos[ns], vel[ns]
    for (int part = 0; part < 4; ++part) {
        const int    node = (part < 2) ? nd : ns;
        const float* base = (part & 1) ? vel : pos;
        const float4* xp  = reinterpret_cast<const float4*>(base + (size_t)node * 32);
        const float*  wp  = w1 + part * 32 * 64;
        for (int q = 0; q < 8; ++q) {
            const float4 xv = xp[q];
#pragma unroll
            for (int kk = 0; kk < 4; ++kk) {
                const float xs = (kk == 0) ? xv.x : (kk == 1) ? xv.y
                               : (kk == 2) ? xv.z : xv.w;
                const float* wr = wp + (q * 4 + kk) * 64;
#pragma unroll
                for (int j = 0; j < 64; ++j)
                    y[j] = fmaf(xs, wr[j], y[j]);
            }
        }
    }

    // layer 2 (fully unrolled so y[] / m[] stay in registers)
    float m[64];
#pragma unroll
    for (int c = 0; c < 64; ++c) m[c] = b2[c];
#pragma unroll
    for (int j = 0; j < 64; ++j) {
        const float  yj = fmaxf(y[j], 0.0f);
        const float* wr = w2 + j * 64;
#pragma unroll
        for (int c = 0; c < 64; ++c) m[c] = fmaf(yj, wr[c], m[c]);
    }

    float* ap = aggr + (size_t)nd * 64;
#pragma unroll
    for (int c = 0; c < 64; ++c) atomicAdd(ap + c, m[c]);
}

// ---------------------------------------------------------------------------
// Node kernel: one thread per node.
//   x = [h(64), aggr(64)] ; u = relu(x@uw1+ub1)@uw2+ub2 ; out = u@pw+pb
// ---------------------------------------------------------------------------
extern "C" __global__ void __launch_bounds__(256)
node_upd_kernel(const float* __restrict__ pos,
                const float* __restrict__ vel,
                const float* __restrict__ aggr,
                const float* __restrict__ w1,
                const float* __restrict__ b1,
                const float* __restrict__ w2,
                const float* __restrict__ b2,
                const float* __restrict__ pw,
                const float* __restrict__ pb,
                float* __restrict__ out)
{
    const int v = blockIdx.x * 256 + threadIdx.x;
    if (v >= NN) return;

    float y[64];
#pragma unroll
    for (int j = 0; j < 64; ++j) y[j] = b1[j];

    // layer 1: 4 parts of 32 inputs: pos[v], vel[v], aggr[v][0:32], aggr[v][32:64]
    for (int part = 0; part < 4; ++part) {
        const float* base = (part == 0) ? pos + (size_t)v * 32
                          : (part == 1) ? vel + (size_t)v * 32
                          : aggr + (size_t)v * 64 + (size_t)(part - 2) * 32;
        const float4* xp = reinterpret_cast<const float4*>(base);
        const float*  wp = w1 + part * 32 * 64;
        for (int q = 0; q < 8; ++q) {
            const float4 xv = xp[q];
#pragma unroll
            for (int kk = 0; kk < 4; ++kk) {
                const float xs = (kk == 0) ? xv.x : (kk == 1) ? xv.y
                               : (kk == 2) ? xv.z : xv.w;
                const float* wr = wp + (q * 4 + kk) * 64;
#pragma unroll
                for (int j = 0; j < 64; ++j)
                    y[j] = fmaf(xs, wr[j], y[j]);
            }
        }
    }

    float u[64];
#pragma unroll
    for (int c = 0; c < 64; ++c) u[c] = b2[c];
#pragma unroll
    for (int j = 0; j < 64; ++j) {
        const float  yj = fmaxf(y[j], 0.0f);
        const float* wr = w2 + j * 64;
#pragma unroll
        for (int c = 0; c < 64; ++c) u[c] = fmaf(yj, wr[c], u[c]);
    }

    float o[32];
#pragma unroll
    for (int c = 0; c < 32; ++c) o[c] = pb[c];
#pragma unroll
    for (int j = 0; j < 64; ++j) {
        const float* wr = pw + j * 32;
#pragma unroll
        for (int c = 0; c < 32; ++c) o[c] = fmaf(u[j], wr[c], o[c]);
    }

    float4* op = reinterpret_cast<float4*>(out + (size_t)v * 32);
#pragma unroll
    for (int q = 0; q < 8; ++q)
        op[q] = make_float4(o[q * 4], o[q * 4 + 1], o[q * 4 + 2], o[q * 4 + 3]);
}

extern "C" void kernel_launch(void* const* d_in, const int* in_sizes, int n_in,
                              void* d_out, int out_size, void* d_ws, size_t ws_size,
                              hipStream_t stream)
{
    const float* pos = (const float*)d_in[0];
    const float* vel = (const float*)d_in[1];
    const int*   ei  = (const int*)d_in[2];
    const float* mw1 = (const float*)d_in[3];
    const float* mb1 = (const float*)d_in[4];
    const float* mw2 = (const float*)d_in[5];
    const float* mb2 = (const float*)d_in[6];
    const float* uw1 = (const float*)d_in[7];
    const float* ub1 = (const float*)d_in[8];
    const float* uw2 = (const float*)d_in[9];
    const float* ub2 = (const float*)d_in[10];
    const float* pw  = (const float*)d_in[11];
    const float* pb  = (const float*)d_in[12];
    float* out  = (float*)d_out;
    float* aggr = (float*)d_ws;   // [NN, 64] fp32 = 25.6 MB

    hipMemsetAsync(aggr, 0, (size_t)NN * 64 * sizeof(float), stream);

    edge_msg_kernel<<<NE / 256, 256, 0, stream>>>(pos, vel, ei,
                                                  mw1, mb1, mw2, mb2, aggr);
    node_upd_kernel<<<(NN + 255) / 256, 256, 0, stream>>>(pos, vel, aggr,
                                                          uw1, ub1, uw2, ub2,
                                                          pw, pb, out);
}

// Round 2
// 1330.507 us; speedup vs baseline: 4.2839x; 4.2839x over previous
//
#include <hip/hip_runtime.h>

#define NN 100000
#define NE 1600000
#define NBLK ((NN + 255) / 256)   // 391 scan blocks

// ---------------- helpers: bf16 storage ----------------
__device__ __forceinline__ unsigned short f2bf(float x) {
    union { float f; unsigned int u; } c; c.f = x;
    unsigned int r = (c.u + 0x7fffu + ((c.u >> 16) & 1u)) >> 16;  // RNE
    return (unsigned short)r;
}
__device__ __forceinline__ float bf2f(unsigned short b) {
    union { unsigned int u; float f; } c; c.u = ((unsigned int)b) << 16;
    return c.f;
}

// ---------------- pass 1: histogram of dst ----------------
extern "C" __global__ void __launch_bounds__(256)
hist_kernel(const int* __restrict__ ei, int* __restrict__ cnt)
{
    const int e = blockIdx.x * 256 + threadIdx.x;
    if (e < NE) atomicAdd(&cnt[ei[NE + e]], 1);
}

// ---------------- pass 2a: per-block partial sums ----------------
extern "C" __global__ void __launch_bounds__(256)
partial_kernel(const int* __restrict__ cnt, int* __restrict__ partial)
{
    __shared__ int s[256];
    const int tid = threadIdx.x;
    const int i = blockIdx.x * 256 + tid;
    s[tid] = (i < NN) ? cnt[i] : 0;
    __syncthreads();
    for (int off = 128; off > 0; off >>= 1) {
        if (tid < off) s[tid] += s[tid + off];
        __syncthreads();
    }
    if (tid == 0) partial[blockIdx.x] = s[0];
}

// ---------------- pass 2b: scan block partials (1 block) ----------------
extern "C" __global__ void __launch_bounds__(512)
scanoff_kernel(const int* __restrict__ partial, int* __restrict__ blockoff)
{
    __shared__ int s[512];
    const int tid = threadIdx.x;
    s[tid] = (tid < NBLK) ? partial[tid] : 0;
    __syncthreads();
    for (int off = 1; off < 512; off <<= 1) {
        int v = (tid >= off) ? s[tid - off] : 0;
        __syncthreads();
        s[tid] += v;
        __syncthreads();
    }
    if (tid < NBLK) blockoff[tid] = (tid == 0) ? 0 : s[tid - 1];  // exclusive
}

// ---------------- pass 2c: per-element base + cursor init ----------------
extern "C" __global__ void __launch_bounds__(256)
base_kernel(const int* __restrict__ cnt, const int* __restrict__ blockoff,
            int* __restrict__ base, int* __restrict__ cur)
{
    __shared__ int s[256];
    const int tid = threadIdx.x;
    const int i = blockIdx.x * 256 + tid;
    const int c = (i < NN) ? cnt[i] : 0;
    s[tid] = c;
    __syncthreads();
    for (int off = 1; off < 256; off <<= 1) {
        int v = (tid >= off) ? s[tid - off] : 0;
        __syncthreads();
        s[tid] += v;
        __syncthreads();
    }
    if (i < NN) {
        const int b = blockoff[blockIdx.x] + s[tid] - c;  // exclusive within block
        base[i] = b;
        cur[i]  = b;
    }
}

// ---------------- pass 3: edge MLP -> sorted message rows ----------------
template <typename MT>
__global__ void __launch_bounds__(256)
edge_sorted_kernel(const float* __restrict__ pos,
                   const float* __restrict__ vel,
                   const int*   __restrict__ ei,
                   const float* __restrict__ w1,
                   const float* __restrict__ b1,
                   const float* __restrict__ w2,
                   const float* __restrict__ b2,
                   int* __restrict__ cur,
                   MT*  __restrict__ msg)
{
    const int e = blockIdx.x * 256 + threadIdx.x;
    if (e >= NE) return;
    const int ns = ei[e];
    const int nd = ei[NE + e];

    float y[64];
#pragma unroll
    for (int j = 0; j < 64; ++j) y[j] = b1[j];

    for (int part = 0; part < 4; ++part) {
        const int    node = (part < 2) ? nd : ns;
        const float* basep = (part & 1) ? vel : pos;
        const float4* xp  = reinterpret_cast<const float4*>(basep + (size_t)node * 32);
        const float*  wp  = w1 + part * 32 * 64;
        for (int q = 0; q < 8; ++q) {
            const float4 xv = xp[q];
#pragma unroll
            for (int kk = 0; kk < 4; ++kk) {
                const float xs = (kk == 0) ? xv.x : (kk == 1) ? xv.y
                               : (kk == 2) ? xv.z : xv.w;
                const float* wr = wp + (q * 4 + kk) * 64;
#pragma unroll
                for (int j = 0; j < 64; ++j)
                    y[j] = fmaf(xs, wr[j], y[j]);
            }
        }
    }

    float m[64];
#pragma unroll
    for (int c = 0; c < 64; ++c) m[c] = b2[c];
#pragma unroll
    for (int j = 0; j < 64; ++j) {
        const float  yj = fmaxf(y[j], 0.0f);
        const float* wr = w2 + j * 64;
#pragma unroll
        for (int c = 0; c < 64; ++c) m[c] = fmaf(yj, wr[c], m[c]);
    }

    const int slot = atomicAdd(&cur[nd], 1);

    if constexpr (sizeof(MT) == 4) {           // fp32 rows
        float4* row = reinterpret_cast<float4*>((float*)msg + (size_t)slot * 64);
#pragma unroll
        for (int q = 0; q < 16; ++q)
            row[q] = make_float4(m[q * 4], m[q * 4 + 1], m[q * 4 + 2], m[q * 4 + 3]);
    } else {                                   // bf16 rows
        uint4* row = reinterpret_cast<uint4*>((unsigned short*)msg + (size_t)slot * 64);
#pragma unroll
        for (int q = 0; q < 8; ++q) {
            uint4 p;
            p.x = (unsigned)f2bf(m[q*8+0]) | ((unsigned)f2bf(m[q*8+1]) << 16);
            p.y = (unsigned)f2bf(m[q*8+2]) | ((unsigned)f2bf(m[q*8+3]) << 16);
            p.z = (unsigned)f2bf(m[q*8+4]) | ((unsigned)f2bf(m[q*8+5]) << 16);
            p.w = (unsigned)f2bf(m[q*8+6]) | ((unsigned)f2bf(m[q*8+7]) << 16);
            row[q] = p;
        }
    }
}

// ---------------- pass 4: wave-per-node aggregation ----------------
template <typename MT>
__global__ void __launch_bounds__(256)
agg_kernel(const MT* __restrict__ msg, const int* __restrict__ base,
           const int* __restrict__ cnt, float* __restrict__ aggr)
{
    const int wave = threadIdx.x >> 6;
    const int lane = threadIdx.x & 63;
    const int v = blockIdx.x * 4 + wave;
    if (v >= NN) return;
    const int b = base[v];
    const int n = cnt[v];
    float acc = 0.0f;
    for (int k = 0; k < n; ++k) {
        if constexpr (sizeof(MT) == 4)
            acc += ((const float*)msg)[(size_t)(b + k) * 64 + lane];
        else
            acc += bf2f(((const unsigned short*)msg)[(size_t)(b + k) * 64 + lane]);
    }
    aggr[(size_t)v * 64 + lane] = acc;
}

// ---------------- fallback: original atomic edge kernel ----------------
extern "C" __global__ void __launch_bounds__(256)
edge_msg_kernel(const float* __restrict__ pos,
                const float* __restrict__ vel,
                const int*   __restrict__ ei,
                const float* __restrict__ w1,
                const float* __restrict__ b1,
                const float* __restrict__ w2,
                const float* __restrict__ b2,
                float* __restrict__ aggr)
{
    const int e = blockIdx.x * 256 + threadIdx.x;
    if (e >= NE) return;
    const int ns = ei[e];
    const int nd = ei[NE + e];

    float y[64];
#pragma unroll
    for (int j = 0; j < 64; ++j) y[j] = b1[j];
    for (int part = 0; part < 4; ++part) {
        const int    node = (part < 2) ? nd : ns;
        const float* basep = (part & 1) ? vel : pos;
        const float4* xp  = reinterpret_cast<const float4*>(basep + (size_t)node * 32);
        const float*  wp  = w1 + part * 32 * 64;
        for (int q = 0; q < 8; ++q) {
            const float4 xv = xp[q];
#pragma unroll
            for (int kk = 0; kk < 4; ++kk) {
                const float xs = (kk == 0) ? xv.x : (kk == 1) ? xv.y
                               : (kk == 2) ? xv.z : xv.w;
                const float* wr = wp + (q * 4 + kk) * 64;
#pragma unroll
                for (int j = 0; j < 64; ++j)
                    y[j] = fmaf(xs, wr[j], y[j]);
            }
        }
    }
    float m[64];
#pragma unroll
    for (int c = 0; c < 64; ++c) m[c] = b2[c];
#pragma unroll
    for (int j = 0; j < 64; ++j) {
        const float  yj = fmaxf(y[j], 0.0f);
        const float* wr = w2 + j * 64;
#pragma unroll
        for (int c = 0; c < 64; ++c) m[c] = fmaf(yj, wr[c], m[c]);
    }
    float* ap = aggr + (size_t)nd * 64;
#pragma unroll
    for (int c = 0; c < 64; ++c) atomicAdd(ap + c, m[c]);
}

// ---------------- node update MLP (unchanged) ----------------
extern "C" __global__ void __launch_bounds__(256)
node_upd_kernel(const float* __restrict__ pos,
                const float* __restrict__ vel,
                const float* __restrict__ aggr,
                const float* __restrict__ w1,
                const float* __restrict__ b1,
                const float* __restrict__ w2,
                const float* __restrict__ b2,
                const float* __restrict__ pw,
                const float* __restrict__ pb,
                float* __restrict__ out)
{
    const int v = blockIdx.x * 256 + threadIdx.x;
    if (v >= NN) return;

    float y[64];
#pragma unroll
    for (int j = 0; j < 64; ++j) y[j] = b1[j];

    for (int part = 0; part < 4; ++part) {
        const float* basep = (part == 0) ? pos + (size_t)v * 32
                           : (part == 1) ? vel + (size_t)v * 32
                           : aggr + (size_t)v * 64 + (size_t)(part - 2) * 32;
        const float4* xp = reinterpret_cast<const float4*>(basep);
        const float*  wp = w1 + part * 32 * 64;
        for (int q = 0; q < 8; ++q) {
            const float4 xv = xp[q];
#pragma unroll
            for (int kk = 0; kk < 4; ++kk) {
                const float xs = (kk == 0) ? xv.x : (kk == 1) ? xv.y
                               : (kk == 2) ? xv.z : xv.w;
                const float* wr = wp + (q * 4 + kk) * 64;
#pragma unroll
                for (int j = 0; j < 64; ++j)
                    y[j] = fmaf(xs, wr[j], y[j]);
            }
        }
    }

    float u[64];
#pragma unroll
    for (int c = 0; c < 64; ++c) u[c] = b2[c];
#pragma unroll
    for (int j = 0; j < 64; ++j) {
        const float  yj = fmaxf(y[j], 0.0f);
        const float* wr = w2 + j * 64;
#pragma unroll
        for (int c = 0; c < 64; ++c) u[c] = fmaf(yj, wr[c], u[c]);
    }

    float o[32];
#pragma unroll
    for (int c = 0; c < 32; ++c) o[c] = pb[c];
#pragma unroll
    for (int j = 0; j < 64; ++j) {
        const float* wr = pw + j * 32;
#pragma unroll
        for (int c = 0; c < 32; ++c) o[c] = fmaf(u[j], wr[c], o[c]);
    }

    float4* op = reinterpret_cast<float4*>(out + (size_t)v * 32);
#pragma unroll
    for (int q = 0; q < 8; ++q)
        op[q] = make_float4(o[q * 4], o[q * 4 + 1], o[q * 4 + 2], o[q * 4 + 3]);
}

// ---------------- launcher ----------------
extern "C" void kernel_launch(void* const* d_in, const int* in_sizes, int n_in,
                              void* d_out, int out_size, void* d_ws, size_t ws_size,
                              hipStream_t stream)
{
    const float* pos = (const float*)d_in[0];
    const float* vel = (const float*)d_in[1];
    const int*   ei  = (const int*)d_in[2];
    const float* mw1 = (const float*)d_in[3];
    const float* mb1 = (const float*)d_in[4];
    const float* mw2 = (const float*)d_in[5];
    const float* mb2 = (const float*)d_in[6];
    const float* uw1 = (const float*)d_in[7];
    const float* ub1 = (const float*)d_in[8];
    const float* uw2 = (const float*)d_in[9];
    const float* ub2 = (const float*)d_in[10];
    const float* pw  = (const float*)d_in[11];
    const float* pb  = (const float*)d_in[12];
    float* out = (float*)d_out;

    // workspace layout
    char* ws = (char*)d_ws;
    int* cnt      = (int*)ws;                       // NN
    int* base     = cnt + NN;                       // NN
    int* cur      = base + NN;                      // NN
    int* partial  = cur + NN;                       // NBLK (<512)
    int* blockoff = partial + 512;                  // NBLK
    size_t intBytes = ((size_t)(3 * NN) + 1024) * sizeof(int);
    size_t msgOff   = (intBytes + 1023) & ~(size_t)1023;

    const size_t msgF32  = (size_t)NE * 64 * sizeof(float);
    const size_t msgBF16 = (size_t)NE * 64 * sizeof(unsigned short);
    const size_t aggrB   = (size_t)NN * 64 * sizeof(float);

    const size_t needF32  = msgOff + msgF32  + aggrB;
    const size_t needBF16 = msgOff + msgBF16 + aggrB;

    if (ws_size >= needBF16) {
        const bool useF32 = (ws_size >= needF32);
        void*  msg  = ws + msgOff;
        float* aggr = (float*)(ws + msgOff + (useF32 ? msgF32 : msgBF16));

        hipMemsetAsync(cnt, 0, (size_t)NN * sizeof(int), stream);
        hist_kernel<<<(NE + 255) / 256, 256, 0, stream>>>(ei, cnt);
        partial_kernel<<<NBLK, 256, 0, stream>>>(cnt, partial);
        scanoff_kernel<<<1, 512, 0, stream>>>(partial, blockoff);
        base_kernel<<<NBLK, 256, 0, stream>>>(cnt, blockoff, base, cur);
        if (useF32) {
            edge_sorted_kernel<float><<<NE / 256, 256, 0, stream>>>(
                pos, vel, ei, mw1, mb1, mw2, mb2, cur, (float*)msg);
            agg_kernel<float><<<(NN + 3) / 4, 256, 0, stream>>>(
                (const float*)msg, base, cnt, aggr);
        } else {
            edge_sorted_kernel<unsigned short><<<NE / 256, 256, 0, stream>>>(
                pos, vel, ei, mw1, mb1, mw2, mb2, cur, (unsigned short*)msg);
            agg_kernel<unsigned short><<<(NN + 3) / 4, 256, 0, stream>>>(
                (const unsigned short*)msg, base, cnt, aggr);
        }
        node_upd_kernel<<<(NN + 255) / 256, 256, 0, stream>>>(
            pos, vel, aggr, uw1, ub1, uw2, ub2, pw, pb, out);
    } else {
        // fallback: atomic path (needs only 25.6 MB)
        float* aggr = (float*)d_ws;
        hipMemsetAsync(aggr, 0, aggrB, stream);
        edge_msg_kernel<<<NE / 256, 256, 0, stream>>>(pos, vel, ei,
                                                      mw1, mb1, mw2, mb2, aggr);
        node_upd_kernel<<<(NN + 255) / 256, 256, 0, stream>>>(
            pos, vel, aggr, uw1, ub1, uw2, ub2, pw, pb, out);
    }
}

// Round 3
// 425.159 us; speedup vs baseline: 13.4063x; 3.1294x over previous
//
#include <hip/hip_runtime.h>

#define NN 100000
#define NE 1600000
#define NBLK ((NN + 255) / 256)   // 391 scan blocks

typedef _Float16 f16x8 __attribute__((ext_vector_type(8)));
typedef float    f32x4 __attribute__((ext_vector_type(4)));

// ===================== pre-pack kernels =====================

// pack h = [pos|vel] -> fp16 table hh[NN][64]; thread = 8 contiguous elems
extern "C" __global__ void __launch_bounds__(256)
pack_h_kernel(const float* __restrict__ pos, const float* __restrict__ vel,
              _Float16* __restrict__ hh)
{
    const int t = blockIdx.x * 256 + threadIdx.x;      // NN*8 threads
    const int node = t >> 3, seg = t & 7;
    const float* src = (seg < 4) ? pos + (size_t)node * 32 + seg * 8
                                 : vel + (size_t)node * 32 + (seg - 4) * 8;
    const float4 a = ((const float4*)src)[0];
    const float4 b = ((const float4*)src)[1];
    f16x8 r;
    r[0]=(_Float16)a.x; r[1]=(_Float16)a.y; r[2]=(_Float16)a.z; r[3]=(_Float16)a.w;
    r[4]=(_Float16)b.x; r[5]=(_Float16)b.y; r[6]=(_Float16)b.z; r[7]=(_Float16)b.w;
    *(f16x8*)(hh + (size_t)node * 64 + seg * 8) = r;
}

// pack W1/W2 into MFMA B-fragment order (fp16)
// w1f[((t*4+kk)*64+l)*8+j] = w1[(kk*32+(l>>4)*8+j)*64 + t*16 + (l&15)]
// w2f[((t*2+kk)*64+l)*8+j] = w2[(kk*32+(l>>4)*8+j)*64 + t*16 + (l&15)]
extern "C" __global__ void __launch_bounds__(256)
pack_w_kernel(const float* __restrict__ w1, const float* __restrict__ w2,
              _Float16* __restrict__ w1f, _Float16* __restrict__ w2f)
{
    const int tid = blockIdx.x * 256 + threadIdx.x;    // 1536 threads
    if (tid < 1024) {
        const int t = tid >> 8, kk = (tid >> 6) & 3, l = tid & 63;
        f16x8 r;
#pragma unroll
        for (int j = 0; j < 8; ++j)
            r[j] = (_Float16)w1[(kk * 32 + (l >> 4) * 8 + j) * 64 + t * 16 + (l & 15)];
        *(f16x8*)(w1f + (size_t)tid * 8) = r;
    } else if (tid < 1536) {
        const int i = tid - 1024;
        const int t = i >> 7, kk = (i >> 6) & 1, l = i & 63;
        f16x8 r;
#pragma unroll
        for (int j = 0; j < 8; ++j)
            r[j] = (_Float16)w2[(kk * 32 + (l >> 4) * 8 + j) * 64 + t * 16 + (l & 15)];
        *(f16x8*)(w2f + (size_t)i * 8) = r;
    }
}

// ===================== CSR build =====================

extern "C" __global__ void __launch_bounds__(256)
hist_kernel(const int* __restrict__ ei, int* __restrict__ cnt)
{
    const int e = blockIdx.x * 256 + threadIdx.x;
    if (e < NE) atomicAdd(&cnt[ei[NE + e]], 1);
}

extern "C" __global__ void __launch_bounds__(256)
partial_kernel(const int* __restrict__ cnt, int* __restrict__ partial)
{
    __shared__ int s[256];
    const int tid = threadIdx.x;
    const int i = blockIdx.x * 256 + tid;
    s[tid] = (i < NN) ? cnt[i] : 0;
    __syncthreads();
    for (int off = 128; off > 0; off >>= 1) {
        if (tid < off) s[tid] += s[tid + off];
        __syncthreads();
    }
    if (tid == 0) partial[blockIdx.x] = s[0];
}

extern "C" __global__ void __launch_bounds__(512)
scanoff_kernel(const int* __restrict__ partial, int* __restrict__ blockoff)
{
    __shared__ int s[512];
    const int tid = threadIdx.x;
    s[tid] = (tid < NBLK) ? partial[tid] : 0;
    __syncthreads();
    for (int off = 1; off < 512; off <<= 1) {
        int v = (tid >= off) ? s[tid - off] : 0;
        __syncthreads();
        s[tid] += v;
        __syncthreads();
    }
    if (tid < NBLK) blockoff[tid] = (tid == 0) ? 0 : s[tid - 1];
}

extern "C" __global__ void __launch_bounds__(256)
base_kernel(const int* __restrict__ cnt, const int* __restrict__ blockoff,
            int* __restrict__ base, int* __restrict__ cur)
{
    __shared__ int s[256];
    const int tid = threadIdx.x;
    const int i = blockIdx.x * 256 + tid;
    const int c = (i < NN) ? cnt[i] : 0;
    s[tid] = c;
    __syncthreads();
    for (int off = 1; off < 256; off <<= 1) {
        int v = (tid >= off) ? s[tid - off] : 0;
        __syncthreads();
        s[tid] += v;
        __syncthreads();
    }
    if (i < NN) {
        const int b = blockoff[blockIdx.x] + s[tid] - c;
        base[i] = b;
        cur[i]  = b;
    }
}

// ===================== MFMA edge kernel =====================
// Block = 256 thr (4 waves); wave handles 16 edges.
// Layer1: A-frags gathered from hh (or pos/vel + cvt), B-frags from LDS-staged w1f.
// Layer2: via XOR-swizzled LDS tile re-fragmentation, B-frags from w2f.
// Output: one int atomic per edge -> slot; coalesced 128B fp16 row write.
template <bool USE_H16>
__global__ void __launch_bounds__(256)
edge_mfma_kernel(const float* __restrict__ pos, const float* __restrict__ vel,
                 const _Float16* __restrict__ hh,
                 const int* __restrict__ ei,
                 const _Float16* __restrict__ w1f, const _Float16* __restrict__ w2f,
                 const float* __restrict__ b1, const float* __restrict__ b2,
                 int* __restrict__ cur, _Float16* __restrict__ msg)
{
    __shared__ _Float16 sW1[4 * 4 * 64 * 8];   // 16 KB
    __shared__ _Float16 sW2[4 * 2 * 64 * 8];   // 8 KB
    __shared__ _Float16 sY[4][16 * 64];        // 8 KB  (layer-2 input tiles)
    __shared__ _Float16 sM[4][16 * 64];        // 8 KB  (output tiles)

    const int tid = threadIdx.x;
    {   // stage W fragments (same 24 KB for every block; L2-broadcast)
        const uint4* g1 = (const uint4*)w1f; uint4* s1 = (uint4*)sW1;
#pragma unroll
        for (int i = 0; i < 4; ++i) s1[i * 256 + tid] = g1[i * 256 + tid];
        const uint4* g2 = (const uint4*)w2f; uint4* s2 = (uint4*)sW2;
#pragma unroll
        for (int i = 0; i < 2; ++i) s2[i * 256 + tid] = g2[i * 256 + tid];
    }
    __syncthreads();

    const int wave = tid >> 6, lane = tid & 63;
    const int m = lane & 15, g = lane >> 4;          // frag row / k-group
    const int ebase = blockIdx.x * 64 + wave * 16;   // 16 edges per wave
    const int erow  = ebase + m;

    const int nsrc = ei[erow];
    const int ndst = ei[NE + erow];

    // ---- layer 1: A-fragments (lane: row m, k-cols g*8..g*8+7 of each 32-chunk)
    f16x8 a[4];
    if constexpr (USE_H16) {
        const _Float16* hd = hh + (size_t)ndst * 64 + g * 8;
        const _Float16* hs = hh + (size_t)nsrc * 64 + g * 8;
        a[0] = *(const f16x8*)(hd);
        a[1] = *(const f16x8*)(hd + 32);
        a[2] = *(const f16x8*)(hs);
        a[3] = *(const f16x8*)(hs + 32);
    } else {
#pragma unroll
        for (int kk = 0; kk < 4; ++kk) {
            const int   node = (kk < 2) ? ndst : nsrc;
            const float* bp  = ((kk & 1) ? vel : pos) + (size_t)node * 32 + g * 8;
            const float4 x0 = ((const float4*)bp)[0];
            const float4 x1 = ((const float4*)bp)[1];
            f16x8 r;
            r[0]=(_Float16)x0.x; r[1]=(_Float16)x0.y; r[2]=(_Float16)x0.z; r[3]=(_Float16)x0.w;
            r[4]=(_Float16)x1.x; r[5]=(_Float16)x1.y; r[6]=(_Float16)x1.z; r[7]=(_Float16)x1.w;
            a[kk] = r;
        }
    }

    f32x4 acc[4] = {};
#pragma unroll
    for (int kk = 0; kk < 4; ++kk) {
#pragma unroll
        for (int t = 0; t < 4; ++t) {
            const f16x8 b = *(const f16x8*)(sW1 + ((t * 4 + kk) * 64 + lane) * 8);
            acc[t] = __builtin_amdgcn_mfma_f32_16x16x32_f16(a[kk], b, acc[t], 0, 0, 0);
        }
    }

    // ---- bias + relu -> fp16 -> swizzled LDS Y tile (row-major [16][64], XOR swz)
    _Float16* Y = sY[wave];
#pragma unroll
    for (int t = 0; t < 4; ++t) {
        const float bb = b1[t * 16 + m];
#pragma unroll
        for (int r = 0; r < 4; ++r) {
            const float y = fmaxf(acc[t][r] + bb, 0.0f);
            const int row = g * 4 + r, col = t * 16 + m;
            const int byteoff = row * 128 + ((2 * col) ^ ((row & 7) << 4));
            *(_Float16*)((char*)Y + byteoff) = (_Float16)y;
        }
    }
    __syncthreads();

    // ---- layer 2: A-frags from swizzled Y, B-frags from sW2
    f32x4 acc2[4] = {};
#pragma unroll
    for (int kk = 0; kk < 2; ++kk) {
        const int c = kk * 4 + g;   // 16B chunk index within row
        const f16x8 a2 = *(const f16x8*)((char*)Y + m * 128 + ((c * 16) ^ ((m & 7) << 4)));
#pragma unroll
        for (int t = 0; t < 4; ++t) {
            const f16x8 b = *(const f16x8*)(sW2 + ((t * 2 + kk) * 64 + lane) * 8);
            acc2[t] = __builtin_amdgcn_mfma_f32_16x16x32_f16(a2, b, acc2[t], 0, 0, 0);
        }
    }

    // ---- bias -> fp16 -> swizzled LDS M tile
    _Float16* M = sM[wave];
#pragma unroll
    for (int t = 0; t < 4; ++t) {
        const float bb = b2[t * 16 + m];
#pragma unroll
        for (int r = 0; r < 4; ++r) {
            const float mv = acc2[t][r] + bb;
            const int row = g * 4 + r, col = t * 16 + m;
            const int byteoff = row * 128 + ((2 * col) ^ ((row & 7) << 4));
            *(_Float16*)((char*)M + byteoff) = (_Float16)mv;
        }
    }
    __syncthreads();

    // ---- slot + coalesced row write (4 lanes per edge, 32 B each)
    int slot;
    if (lane < 16) slot = atomicAdd(&cur[ndst], 1);   // lane<16 => m==lane
    const int row = lane >> 2, seg = lane & 3;
    const int s = __shfl(slot, row, 64);
    const uint4 o0 = *(const uint4*)((char*)M + row * 128 + (((seg * 2    ) * 16) ^ ((row & 7) << 4)));
    const uint4 o1 = *(const uint4*)((char*)M + row * 128 + (((seg * 2 + 1) * 16) ^ ((row & 7) << 4)));
    uint4* dp = (uint4*)((char*)msg + (size_t)s * 128 + seg * 32);
    dp[0] = o0;
    dp[1] = o1;
}

// ===================== aggregation (wave per node) =====================
extern "C" __global__ void __launch_bounds__(256)
agg_kernel(const _Float16* __restrict__ msg, const int* __restrict__ base,
           const int* __restrict__ cnt, float* __restrict__ aggr)
{
    const int wave = threadIdx.x >> 6;
    const int lane = threadIdx.x & 63;
    const int v = blockIdx.x * 4 + wave;
    if (v >= NN) return;
    const int b = base[v];
    const int n = cnt[v];
    float acc = 0.0f;
    for (int k = 0; k < n; ++k)
        acc += (float)msg[(size_t)(b + k) * 64 + lane];
    aggr[(size_t)v * 64 + lane] = acc;
}

// ===================== fallback: atomic edge kernel =====================
extern "C" __global__ void __launch_bounds__(256)
edge_msg_kernel(const float* __restrict__ pos, const float* __restrict__ vel,
                const int* __restrict__ ei,
                const float* __restrict__ w1, const float* __restrict__ b1,
                const float* __restrict__ w2, const float* __restrict__ b2,
                float* __restrict__ aggr)
{
    const int e = blockIdx.x * 256 + threadIdx.x;
    if (e >= NE) return;
    const int ns = ei[e];
    const int nd = ei[NE + e];
    float y[64];
#pragma unroll
    for (int j = 0; j < 64; ++j) y[j] = b1[j];
    for (int part = 0; part < 4; ++part) {
        const int    node  = (part < 2) ? nd : ns;
        const float* basep = (part & 1) ? vel : pos;
        const float4* xp = reinterpret_cast<const float4*>(basep + (size_t)node * 32);
        const float*  wp = w1 + part * 32 * 64;
        for (int q = 0; q < 8; ++q) {
            const float4 xv = xp[q];
#pragma unroll
            for (int kk = 0; kk < 4; ++kk) {
                const float xs = (kk == 0) ? xv.x : (kk == 1) ? xv.y
                               : (kk == 2) ? xv.z : xv.w;
                const float* wr = wp + (q * 4 + kk) * 64;
#pragma unroll
                for (int j = 0; j < 64; ++j) y[j] = fmaf(xs, wr[j], y[j]);
            }
        }
    }
    float mm[64];
#pragma unroll
    for (int c = 0; c < 64; ++c) mm[c] = b2[c];
#pragma unroll
    for (int j = 0; j < 64; ++j) {
        const float yj = fmaxf(y[j], 0.0f);
        const float* wr = w2 + j * 64;
#pragma unroll
        for (int c = 0; c < 64; ++c) mm[c] = fmaf(yj, wr[c], mm[c]);
    }
    float* ap = aggr + (size_t)nd * 64;
#pragma unroll
    for (int c = 0; c < 64; ++c) atomicAdd(ap + c, mm[c]);
}

// ===================== node update MLP =====================
extern "C" __global__ void __launch_bounds__(256)
node_upd_kernel(const float* __restrict__ pos, const float* __restrict__ vel,
                const float* __restrict__ aggr,
                const float* __restrict__ w1, const float* __restrict__ b1,
                const float* __restrict__ w2, const float* __restrict__ b2,
                const float* __restrict__ pw, const float* __restrict__ pb,
                float* __restrict__ out)
{
    const int v = blockIdx.x * 256 + threadIdx.x;
    if (v >= NN) return;

    float y[64];
#pragma unroll
    for (int j = 0; j < 64; ++j) y[j] = b1[j];
    for (int part = 0; part < 4; ++part) {
        const float* basep = (part == 0) ? pos + (size_t)v * 32
                           : (part == 1) ? vel + (size_t)v * 32
                           : aggr + (size_t)v * 64 + (size_t)(part - 2) * 32;
        const float4* xp = reinterpret_cast<const float4*>(basep);
        const float*  wp = w1 + part * 32 * 64;
        for (int q = 0; q < 8; ++q) {
            const float4 xv = xp[q];
#pragma unroll
            for (int kk = 0; kk < 4; ++kk) {
                const float xs = (kk == 0) ? xv.x : (kk == 1) ? xv.y
                               : (kk == 2) ? xv.z : xv.w;
                const float* wr = wp + (q * 4 + kk) * 64;
#pragma unroll
                for (int j = 0; j < 64; ++j) y[j] = fmaf(xs, wr[j], y[j]);
            }
        }
    }

    float u[64];
#pragma unroll
    for (int c = 0; c < 64; ++c) u[c] = b2[c];
#pragma unroll
    for (int j = 0; j < 64; ++j) {
        const float yj = fmaxf(y[j], 0.0f);
        const float* wr = w2 + j * 64;
#pragma unroll
        for (int c = 0; c < 64; ++c) u[c] = fmaf(yj, wr[c], u[c]);
    }

    float o[32];
#pragma unroll
    for (int c = 0; c < 32; ++c) o[c] = pb[c];
#pragma unroll
    for (int j = 0; j < 64; ++j) {
        const float* wr = pw + j * 32;
#pragma unroll
        for (int c = 0; c < 32; ++c) o[c] = fmaf(u[j], wr[c], o[c]);
    }

    float4* op = reinterpret_cast<float4*>(out + (size_t)v * 32);
#pragma unroll
    for (int q = 0; q < 8; ++q)
        op[q] = make_float4(o[q * 4], o[q * 4 + 1], o[q * 4 + 2], o[q * 4 + 3]);
}

// ===================== launcher =====================
extern "C" void kernel_launch(void* const* d_in, const int* in_sizes, int n_in,
                              void* d_out, int out_size, void* d_ws, size_t ws_size,
                              hipStream_t stream)
{
    const float* pos = (const float*)d_in[0];
    const float* vel = (const float*)d_in[1];
    const int*   ei  = (const int*)d_in[2];
    const float* mw1 = (const float*)d_in[3];
    const float* mb1 = (const float*)d_in[4];
    const float* mw2 = (const float*)d_in[5];
    const float* mb2 = (const float*)d_in[6];
    const float* uw1 = (const float*)d_in[7];
    const float* ub1 = (const float*)d_in[8];
    const float* uw2 = (const float*)d_in[9];
    const float* ub2 = (const float*)d_in[10];
    const float* pw  = (const float*)d_in[11];
    const float* pb  = (const float*)d_in[12];
    float* out = (float*)d_out;

    // workspace layout
    char* ws = (char*)d_ws;
    int* cnt      = (int*)ws;            // NN
    int* base     = cnt + NN;            // NN
    int* cur      = base + NN;           // NN
    int* partial  = cur + NN;            // 512
    int* blockoff = partial + 512;       // 512
    size_t off = ((size_t)(3 * NN + 1024) * sizeof(int) + 255) & ~(size_t)255;

    _Float16* msg = (_Float16*)(ws + off);           off += (size_t)NE * 64 * 2;   // 204.8 MB
    float*    aggr = (float*)(ws + off);             off += (size_t)NN * 64 * 4;   // 25.6 MB
    _Float16* w1f = (_Float16*)(ws + off);           off += 4 * 4 * 64 * 8 * 2;    // 16 KB
    _Float16* w2f = (_Float16*)(ws + off);           off += 4 * 2 * 64 * 8 * 2;    // 8 KB
    const size_t need_nohh = off;
    _Float16* hh = (_Float16*)(ws + off);            off += (size_t)NN * 64 * 2;   // 12.8 MB
    const size_t need_hh = off;

    if (ws_size >= need_nohh) {
        const bool useH = (ws_size >= need_hh);

        pack_w_kernel<<<6, 256, 0, stream>>>(mw1, mw2, w1f, w2f);
        if (useH)
            pack_h_kernel<<<NN * 8 / 256, 256, 0, stream>>>(pos, vel, hh);

        hipMemsetAsync(cnt, 0, (size_t)NN * sizeof(int), stream);
        hist_kernel<<<(NE + 255) / 256, 256, 0, stream>>>(ei, cnt);
        partial_kernel<<<NBLK, 256, 0, stream>>>(cnt, partial);
        scanoff_kernel<<<1, 512, 0, stream>>>(partial, blockoff);
        base_kernel<<<NBLK, 256, 0, stream>>>(cnt, blockoff, base, cur);

        if (useH)
            edge_mfma_kernel<true><<<NE / 64, 256, 0, stream>>>(
                pos, vel, hh, ei, w1f, w2f, mb1, mb2, cur, msg);
        else
            edge_mfma_kernel<false><<<NE / 64, 256, 0, stream>>>(
                pos, vel, hh, ei, w1f, w2f, mb1, mb2, cur, msg);

        agg_kernel<<<(NN + 3) / 4, 256, 0, stream>>>(msg, base, cnt, aggr);
        node_upd_kernel<<<(NN + 255) / 256, 256, 0, stream>>>(
            pos, vel, aggr, uw1, ub1, uw2, ub2, pw, pb, out);
    } else {
        // fallback: atomic path (needs only 25.6 MB)
        float* aggr2 = (float*)d_ws;
        hipMemsetAsync(aggr2, 0, (size_t)NN * 64 * sizeof(float), stream);
        edge_msg_kernel<<<NE / 256, 256, 0, stream>>>(pos, vel, ei,
                                                      mw1, mb1, mw2, mb2, aggr2);
        node_upd_kernel<<<(NN + 255) / 256, 256, 0, stream>>>(
            pos, vel, aggr2, uw1, ub1, uw2, ub2, pw, pb, out);
    }
}

// Round 4
// 394.505 us; speedup vs baseline: 14.4480x; 1.0777x over previous
//
#include <hip/hip_runtime.h>

#define NN 100000
#define NE 1600000
#define NBLK ((NN + 255) / 256)   // 391 scan blocks

typedef _Float16 f16x8 __attribute__((ext_vector_type(8)));
typedef _Float16 f16x4 __attribute__((ext_vector_type(4)));
typedef float    f32x4 __attribute__((ext_vector_type(4)));

// ===================== pre-pack kernels =====================

// pack h = [pos|vel] -> fp16 table hh[NN][64]
extern "C" __global__ void __launch_bounds__(256)
pack_h_kernel(const float* __restrict__ pos, const float* __restrict__ vel,
              _Float16* __restrict__ hh)
{
    const int t = blockIdx.x * 256 + threadIdx.x;      // NN*8 threads
    const int node = t >> 3, seg = t & 7;
    const float* src = (seg < 4) ? pos + (size_t)node * 32 + seg * 8
                                 : vel + (size_t)node * 32 + (seg - 4) * 8;
    const float4 a = ((const float4*)src)[0];
    const float4 b = ((const float4*)src)[1];
    f16x8 r;
    r[0]=(_Float16)a.x; r[1]=(_Float16)a.y; r[2]=(_Float16)a.z; r[3]=(_Float16)a.w;
    r[4]=(_Float16)b.x; r[5]=(_Float16)b.y; r[6]=(_Float16)b.z; r[7]=(_Float16)b.w;
    *(f16x8*)(hh + (size_t)node * 64 + seg * 8) = r;
}

// pack W1/W2 into MFMA B-fragment order (fp16)
extern "C" __global__ void __launch_bounds__(256)
pack_w_kernel(const float* __restrict__ w1, const float* __restrict__ w2,
              _Float16* __restrict__ w1f, _Float16* __restrict__ w2f)
{
    const int tid = blockIdx.x * 256 + threadIdx.x;    // 1536 threads
    if (tid < 1024) {
        const int t = tid >> 8, kk = (tid >> 6) & 3, l = tid & 63;
        f16x8 r;
#pragma unroll
        for (int j = 0; j < 8; ++j)
            r[j] = (_Float16)w1[(kk * 32 + (l >> 4) * 8 + j) * 64 + t * 16 + (l & 15)];
        *(f16x8*)(w1f + (size_t)tid * 8) = r;
    } else if (tid < 1536) {
        const int i = tid - 1024;
        const int t = i >> 7, kk = (i >> 6) & 1, l = i & 63;
        f16x8 r;
#pragma unroll
        for (int j = 0; j < 8; ++j)
            r[j] = (_Float16)w2[(kk * 32 + (l >> 4) * 8 + j) * 64 + t * 16 + (l & 15)];
        *(f16x8*)(w2f + (size_t)i * 8) = r;
    }
}

// ===================== CSR build =====================

// histogram; optionally also record each edge's rank within its dst bucket
extern "C" __global__ void __launch_bounds__(256)
hist_kernel(const int* __restrict__ ei, int* __restrict__ cnt,
            int* __restrict__ rank, int writeRank)
{
    const int e = blockIdx.x * 256 + threadIdx.x;
    if (e < NE) {
        const int r = atomicAdd(&cnt[ei[NE + e]], 1);
        if (writeRank) rank[e] = r;
    }
}

// single-kernel scan: block-local prefix + one global atomic for the block
// offset. Node ranges are disjoint+sized correctly; global order is arbitrary
// (aggregation only needs base/cnt, not node-ordered ranges).
extern "C" __global__ void __launch_bounds__(256)
scanbase_kernel(const int* __restrict__ cnt, int* __restrict__ gtot,
                int* __restrict__ base, int* __restrict__ cur)
{
    __shared__ int s[256];
    __shared__ int boff;
    const int tid = threadIdx.x;
    const int i = blockIdx.x * 256 + tid;
    const int c = (i < NN) ? cnt[i] : 0;
    s[tid] = c;
    __syncthreads();
    for (int off = 1; off < 256; off <<= 1) {
        int v = (tid >= off) ? s[tid - off] : 0;
        __syncthreads();
        s[tid] += v;
        __syncthreads();
    }
    if (tid == 255) boff = atomicAdd(gtot, s[255]);
    __syncthreads();
    if (i < NN) {
        const int b = boff + s[tid] - c;
        base[i] = b;
        cur[i]  = b;
    }
}

// ===================== MFMA edge kernel =====================
// Block = 256 thr (4 waves); wave handles 16 edges. LDS: W1 16K + W2 8K +
// per-wave 2K Y/M scratch (shared buffer) = 32 KB -> 5 blocks/CU.
// Only ONE block barrier (after W staging); Y/M tiles are wave-private.
template <bool USE_H16, bool RANKED>
__global__ void __launch_bounds__(256)
edge_mfma_kernel(const float* __restrict__ pos, const float* __restrict__ vel,
                 const _Float16* __restrict__ hh,
                 const int* __restrict__ ei,
                 const _Float16* __restrict__ w1f, const _Float16* __restrict__ w2f,
                 const float* __restrict__ b1, const float* __restrict__ b2,
                 const int* __restrict__ base, const int* __restrict__ rank,
                 int* __restrict__ cur, _Float16* __restrict__ msg)
{
    __shared__ _Float16 sW1[4 * 4 * 64 * 8];   // 16 KB
    __shared__ _Float16 sW2[4 * 2 * 64 * 8];   // 8 KB
    __shared__ _Float16 sT[4][16 * 64];        // 8 KB (wave-private Y then M)

    const int tid = threadIdx.x;
    const int wave = tid >> 6, lane = tid & 63;
    const int m = lane & 15, g = lane >> 4;
    const int ebase = blockIdx.x * 64 + wave * 16;
    const int erow  = ebase + m;

    const int nsrc = ei[erow];
    const int ndst = ei[NE + erow];

    // slot for this wave's 16 edges (computed by lanes 0..15)
    int slot;
    if (lane < 16) {
        if constexpr (RANKED) slot = base[ndst] + rank[erow];
        else                  slot = atomicAdd(&cur[ndst], 1);
    }

    // ---- layer-1 A-fragments: 16B gathers straight from fp16 h table
    f16x8 a[4];
    if constexpr (USE_H16) {
        const _Float16* hd = hh + (size_t)ndst * 64 + g * 8;
        const _Float16* hs = hh + (size_t)nsrc * 64 + g * 8;
        a[0] = *(const f16x8*)(hd);
        a[1] = *(const f16x8*)(hd + 32);
        a[2] = *(const f16x8*)(hs);
        a[3] = *(const f16x8*)(hs + 32);
    } else {
#pragma unroll
        for (int kk = 0; kk < 4; ++kk) {
            const int   node = (kk < 2) ? ndst : nsrc;
            const float* bp  = ((kk & 1) ? vel : pos) + (size_t)node * 32 + g * 8;
            const float4 x0 = ((const float4*)bp)[0];
            const float4 x1 = ((const float4*)bp)[1];
            f16x8 r;
            r[0]=(_Float16)x0.x; r[1]=(_Float16)x0.y; r[2]=(_Float16)x0.z; r[3]=(_Float16)x0.w;
            r[4]=(_Float16)x1.x; r[5]=(_Float16)x1.y; r[6]=(_Float16)x1.z; r[7]=(_Float16)x1.w;
            a[kk] = r;
        }
    }

    {   // stage W fragments (24 KB, block-shared)
        const uint4* g1 = (const uint4*)w1f; uint4* s1 = (uint4*)sW1;
#pragma unroll
        for (int i = 0; i < 4; ++i) s1[i * 256 + tid] = g1[i * 256 + tid];
        const uint4* g2 = (const uint4*)w2f; uint4* s2 = (uint4*)sW2;
#pragma unroll
        for (int i = 0; i < 2; ++i) s2[i * 256 + tid] = g2[i * 256 + tid];
    }
    __syncthreads();   // the only block barrier

    // ---- layer 1: 16 MFMAs
    f32x4 acc[4] = {};
#pragma unroll
    for (int kk = 0; kk < 4; ++kk) {
#pragma unroll
        for (int t = 0; t < 4; ++t) {
            const f16x8 b = *(const f16x8*)(sW1 + ((t * 4 + kk) * 64 + lane) * 8);
            acc[t] = __builtin_amdgcn_mfma_f32_16x16x32_f16(a[kk], b, acc[t], 0, 0, 0);
        }
    }

    // ---- bias+relu -> fp16 -> swizzled wave-private Y tile
    _Float16* Y = sT[wave];
#pragma unroll
    for (int t = 0; t < 4; ++t) {
        const float bb = b1[t * 16 + m];
#pragma unroll
        for (int r = 0; r < 4; ++r) {
            const float y = fmaxf(acc[t][r] + bb, 0.0f);
            const int row = g * 4 + r, col = t * 16 + m;
            const int byteoff = row * 128 + ((2 * col) ^ ((row & 7) << 4));
            *(_Float16*)((char*)Y + byteoff) = (_Float16)y;
        }
    }
    asm volatile("s_waitcnt lgkmcnt(0)" ::: "memory");
    __builtin_amdgcn_sched_barrier(0);

    // ---- layer 2: read both A-frags first (buffer is reused for M after)
    f16x8 a2[2];
#pragma unroll
    for (int kk = 0; kk < 2; ++kk) {
        const int c = kk * 4 + g;
        a2[kk] = *(const f16x8*)((char*)Y + m * 128 + ((c * 16) ^ ((m & 7) << 4)));
    }
    asm volatile("s_waitcnt lgkmcnt(0)" ::: "memory");
    __builtin_amdgcn_sched_barrier(0);

    f32x4 acc2[4] = {};
#pragma unroll
    for (int kk = 0; kk < 2; ++kk) {
#pragma unroll
        for (int t = 0; t < 4; ++t) {
            const f16x8 b = *(const f16x8*)(sW2 + ((t * 2 + kk) * 64 + lane) * 8);
            acc2[t] = __builtin_amdgcn_mfma_f32_16x16x32_f16(a2[kk], b, acc2[t], 0, 0, 0);
        }
    }

    // ---- bias -> fp16 -> swizzled M tile (reuses Y buffer)
    _Float16* M = Y;
#pragma unroll
    for (int t = 0; t < 4; ++t) {
        const float bb = b2[t * 16 + m];
#pragma unroll
        for (int r = 0; r < 4; ++r) {
            const float mv = acc2[t][r] + bb;
            const int row = g * 4 + r, col = t * 16 + m;
            const int byteoff = row * 128 + ((2 * col) ^ ((row & 7) << 4));
            *(_Float16*)((char*)M + byteoff) = (_Float16)mv;
        }
    }
    asm volatile("s_waitcnt lgkmcnt(0)" ::: "memory");
    __builtin_amdgcn_sched_barrier(0);

    // ---- coalesced row write: 4 lanes per edge, 2x16B each
    const int row = lane >> 2, seg = lane & 3;
    const int s = __shfl(slot, row, 64);
    const uint4 o0 = *(const uint4*)((char*)M + row * 128 + (((seg * 2    ) * 16) ^ ((row & 7) << 4)));
    const uint4 o1 = *(const uint4*)((char*)M + row * 128 + (((seg * 2 + 1) * 16) ^ ((row & 7) << 4)));
    uint4* dp = (uint4*)((char*)msg + (size_t)s * 128 + seg * 32);
    dp[0] = o0;
    dp[1] = o1;
}

// ===================== aggregation: wave/node, 4 rows per iter =====================
extern "C" __global__ void __launch_bounds__(256)
agg_kernel(const _Float16* __restrict__ msg, const int* __restrict__ base,
           const int* __restrict__ cnt, float* __restrict__ aggr)
{
    const int wave = threadIdx.x >> 6;
    const int lane = threadIdx.x & 63;
    const int v = blockIdx.x * 4 + wave;
    if (v >= NN) return;
    const int b = base[v];
    const int n = cnt[v];
    const int g = lane >> 4, m = lane & 15;

    float a0 = 0.f, a1 = 0.f, a2 = 0.f, a3 = 0.f;
    for (int k = g; k < n; k += 4) {
        const f16x4 x = *(const f16x4*)(msg + (size_t)(b + k) * 64 + m * 4);
        a0 += (float)x[0]; a1 += (float)x[1]; a2 += (float)x[2]; a3 += (float)x[3];
    }
    a0 += __shfl_xor(a0, 16); a1 += __shfl_xor(a1, 16);
    a2 += __shfl_xor(a2, 16); a3 += __shfl_xor(a3, 16);
    a0 += __shfl_xor(a0, 32); a1 += __shfl_xor(a1, 32);
    a2 += __shfl_xor(a2, 32); a3 += __shfl_xor(a3, 32);
    if (lane < 16)
        *(float4*)(aggr + (size_t)v * 64 + m * 4) = make_float4(a0, a1, a2, a3);
}

// ===================== fallback: atomic edge kernel =====================
extern "C" __global__ void __launch_bounds__(256)
edge_msg_kernel(const float* __restrict__ pos, const float* __restrict__ vel,
                const int* __restrict__ ei,
                const float* __restrict__ w1, const float* __restrict__ b1,
                const float* __restrict__ w2, const float* __restrict__ b2,
                float* __restrict__ aggr)
{
    const int e = blockIdx.x * 256 + threadIdx.x;
    if (e >= NE) return;
    const int ns = ei[e];
    const int nd = ei[NE + e];
    float y[64];
#pragma unroll
    for (int j = 0; j < 64; ++j) y[j] = b1[j];
    for (int part = 0; part < 4; ++part) {
        const int    node  = (part < 2) ? nd : ns;
        const float* basep = (part & 1) ? vel : pos;
        const float4* xp = reinterpret_cast<const float4*>(basep + (size_t)node * 32);
        const float*  wp = w1 + part * 32 * 64;
        for (int q = 0; q < 8; ++q) {
            const float4 xv = xp[q];
#pragma unroll
            for (int kk = 0; kk < 4; ++kk) {
                const float xs = (kk == 0) ? xv.x : (kk == 1) ? xv.y
                               : (kk == 2) ? xv.z : xv.w;
                const float* wr = wp + (q * 4 + kk) * 64;
#pragma unroll
                for (int j = 0; j < 64; ++j) y[j] = fmaf(xs, wr[j], y[j]);
            }
        }
    }
    float mm[64];
#pragma unroll
    for (int c = 0; c < 64; ++c) mm[c] = b2[c];
#pragma unroll
    for (int j = 0; j < 64; ++j) {
        const float yj = fmaxf(y[j], 0.0f);
        const float* wr = w2 + j * 64;
#pragma unroll
        for (int c = 0; c < 64; ++c) mm[c] = fmaf(yj, wr[c], mm[c]);
    }
    float* ap = aggr + (size_t)nd * 64;
#pragma unroll
    for (int c = 0; c < 64; ++c) atomicAdd(ap + c, mm[c]);
}

// ===================== node update MLP =====================
extern "C" __global__ void __launch_bounds__(256)
node_upd_kernel(const float* __restrict__ pos, const float* __restrict__ vel,
                const float* __restrict__ aggr,
                const float* __restrict__ w1, const float* __restrict__ b1,
                const float* __restrict__ w2, const float* __restrict__ b2,
                const float* __restrict__ pw, const float* __restrict__ pb,
                float* __restrict__ out)
{
    const int v = blockIdx.x * 256 + threadIdx.x;
    if (v >= NN) return;

    float y[64];
#pragma unroll
    for (int j = 0; j < 64; ++j) y[j] = b1[j];
    for (int part = 0; part < 4; ++part) {
        const float* basep = (part == 0) ? pos + (size_t)v * 32
                           : (part == 1) ? vel + (size_t)v * 32
                           : aggr + (size_t)v * 64 + (size_t)(part - 2) * 32;
        const float4* xp = reinterpret_cast<const float4*>(basep);
        const float*  wp = w1 + part * 32 * 64;
        for (int q = 0; q < 8; ++q) {
            const float4 xv = xp[q];
#pragma unroll
            for (int kk = 0; kk < 4; ++kk) {
                const float xs = (kk == 0) ? xv.x : (kk == 1) ? xv.y
                               : (kk == 2) ? xv.z : xv.w;
                const float* wr = wp + (q * 4 + kk) * 64;
#pragma unroll
                for (int j = 0; j < 64; ++j) y[j] = fmaf(xs, wr[j], y[j]);
            }
        }
    }

    float u[64];
#pragma unroll
    for (int c = 0; c < 64; ++c) u[c] = b2[c];
#pragma unroll
    for (int j = 0; j < 64; ++j) {
        const float yj = fmaxf(y[j], 0.0f);
        const float* wr = w2 + j * 64;
#pragma unroll
        for (int c = 0; c < 64; ++c) u[c] = fmaf(yj, wr[c], u[c]);
    }

    float o[32];
#pragma unroll
    for (int c = 0; c < 32; ++c) o[c] = pb[c];
#pragma unroll
    for (int j = 0; j < 64; ++j) {
        const float* wr = pw + j * 32;
#pragma unroll
        for (int c = 0; c < 32; ++c) o[c] = fmaf(u[j], wr[c], o[c]);
    }

    float4* op = reinterpret_cast<float4*>(out + (size_t)v * 32);
#pragma unroll
    for (int q = 0; q < 8; ++q)
        op[q] = make_float4(o[q * 4], o[q * 4 + 1], o[q * 4 + 2], o[q * 4 + 3]);
}

// ===================== launcher =====================
extern "C" void kernel_launch(void* const* d_in, const int* in_sizes, int n_in,
                              void* d_out, int out_size, void* d_ws, size_t ws_size,
                              hipStream_t stream)
{
    const float* pos = (const float*)d_in[0];
    const float* vel = (const float*)d_in[1];
    const int*   ei  = (const int*)d_in[2];
    const float* mw1 = (const float*)d_in[3];
    const float* mb1 = (const float*)d_in[4];
    const float* mw2 = (const float*)d_in[5];
    const float* mb2 = (const float*)d_in[6];
    const float* uw1 = (const float*)d_in[7];
    const float* ub1 = (const float*)d_in[8];
    const float* uw2 = (const float*)d_in[9];
    const float* ub2 = (const float*)d_in[10];
    const float* pw  = (const float*)d_in[11];
    const float* pb  = (const float*)d_in[12];
    float* out = (float*)d_out;

    // workspace layout
    char* ws = (char*)d_ws;
    int* cnt  = (int*)ws;                 // NN
    int* gtot = cnt + NN;                 // 1   (memset covers cnt+gtot)
    int* base = gtot + 16;                // NN  (16-int pad)
    int* cur  = base + NN;                // NN
    size_t off = ((size_t)(3 * NN + 64) * sizeof(int) + 255) & ~(size_t)255;

    _Float16* msg  = (_Float16*)(ws + off); off += (size_t)NE * 64 * 2;  // 204.8 MB
    float*    aggr = (float*)(ws + off);    off += (size_t)NN * 64 * 4;  // 25.6 MB
    _Float16* w1f  = (_Float16*)(ws + off); off += 4 * 4 * 64 * 8 * 2;   // 16 KB
    _Float16* w2f  = (_Float16*)(ws + off); off += 4 * 2 * 64 * 8 * 2;   // 8 KB
    const size_t need0 = off;
    _Float16* hh   = (_Float16*)(ws + off); off += (size_t)NN * 64 * 2;  // 12.8 MB
    const size_t need_hh = off;
    int*      rank = (int*)(ws + off);      off += (size_t)NE * sizeof(int); // 6.4 MB
    const size_t need_rank = off;

    if (ws_size >= need0) {
        const bool useH    = (ws_size >= need_hh);
        const bool useRank = (ws_size >= need_rank);   // implies useH by layout

        pack_w_kernel<<<6, 256, 0, stream>>>(mw1, mw2, w1f, w2f);
        if (useH)
            pack_h_kernel<<<NN * 8 / 256, 256, 0, stream>>>(pos, vel, hh);

        hipMemsetAsync(cnt, 0, (size_t)(NN + 16) * sizeof(int), stream);
        hist_kernel<<<(NE + 255) / 256, 256, 0, stream>>>(ei, cnt, rank,
                                                          useRank ? 1 : 0);
        scanbase_kernel<<<NBLK, 256, 0, stream>>>(cnt, gtot, base, cur);

        if (useRank)
            edge_mfma_kernel<true, true><<<NE / 64, 256, 0, stream>>>(
                pos, vel, hh, ei, w1f, w2f, mb1, mb2, base, rank, cur, msg);
        else if (useH)
            edge_mfma_kernel<true, false><<<NE / 64, 256, 0, stream>>>(
                pos, vel, hh, ei, w1f, w2f, mb1, mb2, base, rank, cur, msg);
        else
            edge_mfma_kernel<false, false><<<NE / 64, 256, 0, stream>>>(
                pos, vel, hh, ei, w1f, w2f, mb1, mb2, base, rank, cur, msg);

        agg_kernel<<<(NN + 3) / 4, 256, 0, stream>>>(msg, base, cnt, aggr);
        node_upd_kernel<<<(NN + 255) / 256, 256, 0, stream>>>(
            pos, vel, aggr, uw1, ub1, uw2, ub2, pw, pb, out);
    } else {
        // fallback: atomic path (needs only 25.6 MB)
        float* aggr2 = (float*)d_ws;
        hipMemsetAsync(aggr2, 0, (size_t)NN * 64 * sizeof(float), stream);
        edge_msg_kernel<<<NE / 256, 256, 0, stream>>>(pos, vel, ei,
                                                      mw1, mb1, mw2, mb2, aggr2);
        node_upd_kernel<<<(NN + 255) / 256, 256, 0, stream>>>(
            pos, vel, aggr2, uw1, ub1, uw2, ub2, pw, pb, out);
    }
}

// Round 5
// 233.848 us; speedup vs baseline: 24.3739x; 1.6870x over previous
//
#include <hip/hip_runtime.h>

#define NN 100000
#define NE 1600000
#define NBLK ((NN + 255) / 256)   // 391 scan blocks

typedef _Float16 f16x8 __attribute__((ext_vector_type(8)));
typedef float    f32x4 __attribute__((ext_vector_type(4)));

// ===================== pre-pack kernels =====================

// pack h = [pos|vel] -> fp16 table hh[NN][64]
extern "C" __global__ void __launch_bounds__(256)
pack_h_kernel(const float* __restrict__ pos, const float* __restrict__ vel,
              _Float16* __restrict__ hh)
{
    const int t = blockIdx.x * 256 + threadIdx.x;      // NN*8 threads
    const int node = t >> 3, seg = t & 7;
    const float* src = (seg < 4) ? pos + (size_t)node * 32 + seg * 8
                                 : vel + (size_t)node * 32 + (seg - 4) * 8;
    const float4 a = ((const float4*)src)[0];
    const float4 b = ((const float4*)src)[1];
    f16x8 r;
    r[0]=(_Float16)a.x; r[1]=(_Float16)a.y; r[2]=(_Float16)a.z; r[3]=(_Float16)a.w;
    r[4]=(_Float16)b.x; r[5]=(_Float16)b.y; r[6]=(_Float16)b.z; r[7]=(_Float16)b.w;
    *(f16x8*)(hh + (size_t)node * 64 + seg * 8) = r;
}

// pack ALL weights into MFMA B-fragment order (fp16):
//  msg_w1[128,64], msg_w2[64,64], upd_w1[128,64], upd_w2[64,64], pred_w[64,32]
extern "C" __global__ void __launch_bounds__(256)
pack_w_kernel(const float* __restrict__ mw1, const float* __restrict__ mw2,
              const float* __restrict__ uw1, const float* __restrict__ uw2,
              const float* __restrict__ pw,
              _Float16* __restrict__ mw1f, _Float16* __restrict__ mw2f,
              _Float16* __restrict__ uw1f, _Float16* __restrict__ uw2f,
              _Float16* __restrict__ pwf)
{
    const int tid = blockIdx.x * 256 + threadIdx.x;    // 3328 threads
    if (tid < 1024) {                                  // msg_w1
        const int t = tid >> 8, kk = (tid >> 6) & 3, l = tid & 63;
        f16x8 r;
#pragma unroll
        for (int j = 0; j < 8; ++j)
            r[j] = (_Float16)mw1[(kk * 32 + (l >> 4) * 8 + j) * 64 + t * 16 + (l & 15)];
        *(f16x8*)(mw1f + (size_t)tid * 8) = r;
    } else if (tid < 1536) {                           // msg_w2
        const int i = tid - 1024;
        const int t = i >> 7, kk = (i >> 6) & 1, l = i & 63;
        f16x8 r;
#pragma unroll
        for (int j = 0; j < 8; ++j)
            r[j] = (_Float16)mw2[(kk * 32 + (l >> 4) * 8 + j) * 64 + t * 16 + (l & 15)];
        *(f16x8*)(mw2f + (size_t)i * 8) = r;
    } else if (tid < 2560) {                           // upd_w1
        const int i = tid - 1536;
        const int t = i >> 8, kk = (i >> 6) & 3, l = i & 63;
        f16x8 r;
#pragma unroll
        for (int j = 0; j < 8; ++j)
            r[j] = (_Float16)uw1[(kk * 32 + (l >> 4) * 8 + j) * 64 + t * 16 + (l & 15)];
        *(f16x8*)(uw1f + (size_t)i * 8) = r;
    } else if (tid < 3072) {                           // upd_w2
        const int i = tid - 2560;
        const int t = i >> 7, kk = (i >> 6) & 1, l = i & 63;
        f16x8 r;
#pragma unroll
        for (int j = 0; j < 8; ++j)
            r[j] = (_Float16)uw2[(kk * 32 + (l >> 4) * 8 + j) * 64 + t * 16 + (l & 15)];
        *(f16x8*)(uw2f + (size_t)i * 8) = r;
    } else if (tid < 3328) {                           // pred_w [64,32]
        const int i = tid - 3072;
        const int t = i >> 7, kk = (i >> 6) & 1, l = i & 63;
        f16x8 r;
#pragma unroll
        for (int j = 0; j < 8; ++j)
            r[j] = (_Float16)pw[(kk * 32 + (l >> 4) * 8 + j) * 32 + t * 16 + (l & 15)];
        *(f16x8*)(pwf + (size_t)i * 8) = r;
    }
}

// ===================== CSR build =====================

extern "C" __global__ void __launch_bounds__(256)
hist_kernel(const int* __restrict__ ei, int* __restrict__ cnt,
            int* __restrict__ rank)
{
    const int e = blockIdx.x * 256 + threadIdx.x;
    if (e < NE) rank[e] = atomicAdd(&cnt[ei[NE + e]], 1);
}

// single-kernel scan: block-local prefix + one global atomic for block offset.
extern "C" __global__ void __launch_bounds__(256)
scanbase_kernel(const int* __restrict__ cnt, int* __restrict__ gtot,
                int* __restrict__ base)
{
    __shared__ int s[256];
    __shared__ int boff;
    const int tid = threadIdx.x;
    const int i = blockIdx.x * 256 + tid;
    const int c = (i < NN) ? cnt[i] : 0;
    s[tid] = c;
    __syncthreads();
    for (int off = 1; off < 256; off <<= 1) {
        int v = (tid >= off) ? s[tid - off] : 0;
        __syncthreads();
        s[tid] += v;
        __syncthreads();
    }
    if (tid == 255) boff = atomicAdd(gtot, s[255]);
    __syncthreads();
    if (i < NN) base[i] = boff + s[tid] - c;
}

// ===================== MFMA edge kernel (pipelined, 256 edges/block) =====
// Block = 4 waves; wave handles 64 edges in 4 iters of 16.
// ei/rank coalesced (1 load/lane), meta via shfl; iter i+1 gathers issued
// before iter i MFMAs (software pipeline). Only one block barrier.
extern "C" __global__ void __launch_bounds__(256)
edge_mfma_kernel(const _Float16* __restrict__ hh,
                 const int* __restrict__ ei,
                 const _Float16* __restrict__ w1f, const _Float16* __restrict__ w2f,
                 const float* __restrict__ b1, const float* __restrict__ b2,
                 const int* __restrict__ basep, const int* __restrict__ rank,
                 _Float16* __restrict__ msg)
{
    __shared__ _Float16 sW1[4 * 4 * 64 * 8];   // 16 KB
    __shared__ _Float16 sW2[4 * 2 * 64 * 8];   // 8 KB
    __shared__ _Float16 sT[4][16 * 64];        // 8 KB (wave-private Y/M)

    const int tid = threadIdx.x;
    const int wave = tid >> 6, lane = tid & 63;
    const int m = lane & 15, g = lane >> 4;
    const int wbase = (blockIdx.x * 4 + wave) * 64;

    // coalesced per-edge metadata (one edge per lane)
    const int es = ei[wbase + lane];
    const int ed = ei[NE + wbase + lane];
    const int slt = basep[ed] + rank[wbase + lane];

    {   // stage W fragments (24 KB, block-shared, amortized over 256 edges)
        const uint4* g1 = (const uint4*)w1f; uint4* s1 = (uint4*)sW1;
#pragma unroll
        for (int i = 0; i < 4; ++i) s1[i * 256 + tid] = g1[i * 256 + tid];
        const uint4* g2 = (const uint4*)w2f; uint4* s2 = (uint4*)sW2;
#pragma unroll
        for (int i = 0; i < 2; ++i) s2[i * 256 + tid] = g2[i * 256 + tid];
    }

    const float bb1[4] = { b1[m], b1[16 + m], b1[32 + m], b1[48 + m] };
    const float bb2[4] = { b2[m], b2[16 + m], b2[32 + m], b2[48 + m] };

    __syncthreads();   // the only block barrier

    // prefetch iter-0 A-fragments
    f16x8 a0, a1, a2v, a3v;
    {
        const int ns = __shfl(es, m, 64), nd = __shfl(ed, m, 64);
        const _Float16* hd = hh + (size_t)nd * 64 + g * 8;
        const _Float16* hs = hh + (size_t)ns * 64 + g * 8;
        a0 = *(const f16x8*)(hd);      a1 = *(const f16x8*)(hd + 32);
        a2v = *(const f16x8*)(hs);     a3v = *(const f16x8*)(hs + 32);
    }

    _Float16* Y = sT[wave];

#pragma unroll
    for (int it = 0; it < 4; ++it) {
        // issue next iter's gathers early (hidden under this iter's MFMAs)
        f16x8 n0, n1, n2, n3;
        if (it < 3) {
            const int ns = __shfl(es, (it + 1) * 16 + m, 64);
            const int nd = __shfl(ed, (it + 1) * 16 + m, 64);
            const _Float16* hd = hh + (size_t)nd * 64 + g * 8;
            const _Float16* hs = hh + (size_t)ns * 64 + g * 8;
            n0 = *(const f16x8*)(hd);   n1 = *(const f16x8*)(hd + 32);
            n2 = *(const f16x8*)(hs);   n3 = *(const f16x8*)(hs + 32);
        }

        // ---- layer 1: 16 MFMAs
        f32x4 acc[4] = {};
#pragma unroll
        for (int t = 0; t < 4; ++t) {
            acc[t] = __builtin_amdgcn_mfma_f32_16x16x32_f16(
                a0, *(const f16x8*)(sW1 + ((t * 4 + 0) * 64 + lane) * 8), acc[t], 0, 0, 0);
            acc[t] = __builtin_amdgcn_mfma_f32_16x16x32_f16(
                a1, *(const f16x8*)(sW1 + ((t * 4 + 1) * 64 + lane) * 8), acc[t], 0, 0, 0);
            acc[t] = __builtin_amdgcn_mfma_f32_16x16x32_f16(
                a2v, *(const f16x8*)(sW1 + ((t * 4 + 2) * 64 + lane) * 8), acc[t], 0, 0, 0);
            acc[t] = __builtin_amdgcn_mfma_f32_16x16x32_f16(
                a3v, *(const f16x8*)(sW1 + ((t * 4 + 3) * 64 + lane) * 8), acc[t], 0, 0, 0);
        }

        // ---- bias+relu -> fp16 -> swizzled wave-private Y tile
#pragma unroll
        for (int t = 0; t < 4; ++t) {
#pragma unroll
            for (int r = 0; r < 4; ++r) {
                const float y = fmaxf(acc[t][r] + bb1[t], 0.0f);
                const int row = g * 4 + r, col = t * 16 + m;
                const int byteoff = row * 128 + ((2 * col) ^ ((row & 7) << 4));
                *(_Float16*)((char*)Y + byteoff) = (_Float16)y;
            }
        }
        asm volatile("s_waitcnt lgkmcnt(0)" ::: "memory");
        __builtin_amdgcn_sched_barrier(0);

        // ---- layer 2 A-frags from swizzled Y
        f16x8 a2[2];
#pragma unroll
        for (int kk = 0; kk < 2; ++kk) {
            const int c = kk * 4 + g;
            a2[kk] = *(const f16x8*)((char*)Y + m * 128 + ((c * 16) ^ ((m & 7) << 4)));
        }
        asm volatile("s_waitcnt lgkmcnt(0)" ::: "memory");
        __builtin_amdgcn_sched_barrier(0);

        f32x4 acc2[4] = {};
#pragma unroll
        for (int kk = 0; kk < 2; ++kk) {
#pragma unroll
            for (int t = 0; t < 4; ++t) {
                const f16x8 b = *(const f16x8*)(sW2 + ((t * 2 + kk) * 64 + lane) * 8);
                acc2[t] = __builtin_amdgcn_mfma_f32_16x16x32_f16(a2[kk], b, acc2[t], 0, 0, 0);
            }
        }

        // ---- bias -> fp16 -> swizzled M tile (reuses Y buffer)
#pragma unroll
        for (int t = 0; t < 4; ++t) {
#pragma unroll
            for (int r = 0; r < 4; ++r) {
                const float mv = acc2[t][r] + bb2[t];
                const int row = g * 4 + r, col = t * 16 + m;
                const int byteoff = row * 128 + ((2 * col) ^ ((row & 7) << 4));
                *(_Float16*)((char*)Y + byteoff) = (_Float16)mv;
            }
        }
        asm volatile("s_waitcnt lgkmcnt(0)" ::: "memory");
        __builtin_amdgcn_sched_barrier(0);

        // ---- coalesced row write: 4 lanes per edge, 2x16B each
        const int row = lane >> 2, seg = lane & 3;
        const int s = __shfl(slt, it * 16 + row, 64);
        const uint4 o0 = *(const uint4*)((char*)Y + row * 128 + (((seg * 2    ) * 16) ^ ((row & 7) << 4)));
        const uint4 o1 = *(const uint4*)((char*)Y + row * 128 + (((seg * 2 + 1) * 16) ^ ((row & 7) << 4)));
        uint4* dp = (uint4*)((char*)msg + (size_t)s * 128 + seg * 32);
        dp[0] = o0;
        dp[1] = o1;

        // rotate pipeline registers
        if (it < 3) { a0 = n0; a1 = n1; a2v = n2; a3v = n3; }
    }
}

// ===================== aggregation: wave/node, 8 rows/iter, fp16 out =====
extern "C" __global__ void __launch_bounds__(256)
agg_kernel(const _Float16* __restrict__ msg, const int* __restrict__ base,
           const int* __restrict__ cnt, _Float16* __restrict__ ag16)
{
    const int wave = threadIdx.x >> 6;
    const int lane = threadIdx.x & 63;
    const int v = blockIdx.x * 4 + wave;
    if (v >= NN) return;
    const int b = base[v];
    const int n = cnt[v];
    const int r = lane >> 3, c8 = lane & 7;

    float acc[8] = {};
    for (int k = r; k < n; k += 8) {
        const f16x8 x = *(const f16x8*)(msg + (size_t)(b + k) * 64 + c8 * 8);
#pragma unroll
        for (int i = 0; i < 8; ++i) acc[i] += (float)x[i];
    }
#pragma unroll
    for (int i = 0; i < 8; ++i) {
        acc[i] += __shfl_xor(acc[i], 8);
        acc[i] += __shfl_xor(acc[i], 16);
        acc[i] += __shfl_xor(acc[i], 32);
    }
    if (lane < 8) {
        f16x8 o;
#pragma unroll
        for (int i = 0; i < 8; ++i) o[i] = (_Float16)acc[i];
        *(f16x8*)(ag16 + (size_t)v * 64 + c8 * 8) = o;
    }
}

// ===================== MFMA node kernel: agg16+h -> upd MLP -> pred =====
extern "C" __global__ void __launch_bounds__(256)
node_mfma_kernel(const _Float16* __restrict__ hh, const _Float16* __restrict__ ag16,
                 const _Float16* __restrict__ uw1f, const _Float16* __restrict__ uw2f,
                 const _Float16* __restrict__ pwf,
                 const float* __restrict__ b1, const float* __restrict__ b2,
                 const float* __restrict__ pb, float* __restrict__ out)
{
    __shared__ _Float16 sU1[4 * 4 * 64 * 8];   // 16 KB
    __shared__ _Float16 sU2[4 * 2 * 64 * 8];   // 8 KB
    __shared__ _Float16 sPW[2 * 2 * 64 * 8];   // 4 KB
    __shared__ _Float16 sT[4][16 * 64];        // 8 KB

    const int tid = threadIdx.x;
    {
        const uint4* g1 = (const uint4*)uw1f; uint4* s1 = (uint4*)sU1;
#pragma unroll
        for (int i = 0; i < 4; ++i) s1[i * 256 + tid] = g1[i * 256 + tid];
        const uint4* g2 = (const uint4*)uw2f; uint4* s2 = (uint4*)sU2;
#pragma unroll
        for (int i = 0; i < 2; ++i) s2[i * 256 + tid] = g2[i * 256 + tid];
        const uint4* g3 = (const uint4*)pwf;  uint4* s3 = (uint4*)sPW;
        s3[tid] = g3[tid];
    }
    __syncthreads();

    const int wave = tid >> 6, lane = tid & 63;
    const int m = lane & 15, g = lane >> 4;
    const int nb = (blockIdx.x * 4 + wave) * 16;
    const int v = nb + m;
    const int vl = (v < NN) ? v : (NN - 1);

    // A-fragments: x = [h(64) | aggr(64)]
    const _Float16* hv = hh   + (size_t)vl * 64 + g * 8;
    const _Float16* av = ag16 + (size_t)vl * 64 + g * 8;
    const f16x8 a0 = *(const f16x8*)(hv);
    const f16x8 a1 = *(const f16x8*)(hv + 32);
    const f16x8 a2 = *(const f16x8*)(av);
    const f16x8 a3 = *(const f16x8*)(av + 32);

    // layer 1
    f32x4 acc[4] = {};
#pragma unroll
    for (int t = 0; t < 4; ++t) {
        acc[t] = __builtin_amdgcn_mfma_f32_16x16x32_f16(
            a0, *(const f16x8*)(sU1 + ((t * 4 + 0) * 64 + lane) * 8), acc[t], 0, 0, 0);
        acc[t] = __builtin_amdgcn_mfma_f32_16x16x32_f16(
            a1, *(const f16x8*)(sU1 + ((t * 4 + 1) * 64 + lane) * 8), acc[t], 0, 0, 0);
        acc[t] = __builtin_amdgcn_mfma_f32_16x16x32_f16(
            a2, *(const f16x8*)(sU1 + ((t * 4 + 2) * 64 + lane) * 8), acc[t], 0, 0, 0);
        acc[t] = __builtin_amdgcn_mfma_f32_16x16x32_f16(
            a3, *(const f16x8*)(sU1 + ((t * 4 + 3) * 64 + lane) * 8), acc[t], 0, 0, 0);
    }

    _Float16* Y = sT[wave];
#pragma unroll
    for (int t = 0; t < 4; ++t) {
        const float bb = b1[t * 16 + m];
#pragma unroll
        for (int r = 0; r < 4; ++r) {
            const float y = fmaxf(acc[t][r] + bb, 0.0f);
            const int row = g * 4 + r, col = t * 16 + m;
            const int byteoff = row * 128 + ((2 * col) ^ ((row & 7) << 4));
            *(_Float16*)((char*)Y + byteoff) = (_Float16)y;
        }
    }
    asm volatile("s_waitcnt lgkmcnt(0)" ::: "memory");
    __builtin_amdgcn_sched_barrier(0);

    f16x8 ay[2];
#pragma unroll
    for (int kk = 0; kk < 2; ++kk) {
        const int c = kk * 4 + g;
        ay[kk] = *(const f16x8*)((char*)Y + m * 128 + ((c * 16) ^ ((m & 7) << 4)));
    }
    asm volatile("s_waitcnt lgkmcnt(0)" ::: "memory");
    __builtin_amdgcn_sched_barrier(0);

    // layer 2
    f32x4 acc2[4] = {};
#pragma unroll
    for (int kk = 0; kk < 2; ++kk) {
#pragma unroll
        for (int t = 0; t < 4; ++t) {
            const f16x8 b = *(const f16x8*)(sU2 + ((t * 2 + kk) * 64 + lane) * 8);
            acc2[t] = __builtin_amdgcn_mfma_f32_16x16x32_f16(ay[kk], b, acc2[t], 0, 0, 0);
        }
    }

    // u -> fp16 swizzled tile (no relu on layer-2 output)
#pragma unroll
    for (int t = 0; t < 4; ++t) {
        const float bb = b2[t * 16 + m];
#pragma unroll
        for (int r = 0; r < 4; ++r) {
            const float u = acc2[t][r] + bb;
            const int row = g * 4 + r, col = t * 16 + m;
            const int byteoff = row * 128 + ((2 * col) ^ ((row & 7) << 4));
            *(_Float16*)((char*)Y + byteoff) = (_Float16)u;
        }
    }
    asm volatile("s_waitcnt lgkmcnt(0)" ::: "memory");
    __builtin_amdgcn_sched_barrier(0);

    f16x8 au[2];
#pragma unroll
    for (int kk = 0; kk < 2; ++kk) {
        const int c = kk * 4 + g;
        au[kk] = *(const f16x8*)((char*)Y + m * 128 + ((c * 16) ^ ((m & 7) << 4)));
    }
    asm volatile("s_waitcnt lgkmcnt(0)" ::: "memory");
    __builtin_amdgcn_sched_barrier(0);

    // pred head: 64 -> 32
    f32x4 acc3[2] = {};
#pragma unroll
    for (int kk = 0; kk < 2; ++kk) {
#pragma unroll
        for (int t = 0; t < 2; ++t) {
            const f16x8 b = *(const f16x8*)(sPW + ((t * 2 + kk) * 64 + lane) * 8);
            acc3[t] = __builtin_amdgcn_mfma_f32_16x16x32_f16(au[kk], b, acc3[t], 0, 0, 0);
        }
    }

    // fp32 out tile (reuses sT as float[16][32], swizzled 16B chunks)
    float* F = (float*)Y;
#pragma unroll
    for (int t = 0; t < 2; ++t) {
        const float bb = pb[t * 16 + m];
#pragma unroll
        for (int r = 0; r < 4; ++r) {
            const int row = g * 4 + r, col = t * 16 + m;
            const int byteoff = row * 128 + ((4 * col) ^ ((row & 7) << 4));
            *(float*)((char*)F + byteoff) = acc3[t][r] + bb;
        }
    }
    asm volatile("s_waitcnt lgkmcnt(0)" ::: "memory");
    __builtin_amdgcn_sched_barrier(0);

    // coalesced store: 16 rows x 32 floats; lane -> row=lane>>2, chunks q,q+4
    const int row = lane >> 2, q = lane & 3;
    const float4 o0 = *(const float4*)((char*)F + row * 128 + ((q * 16)       ^ ((row & 7) << 4)));
    const float4 o1 = *(const float4*)((char*)F + row * 128 + (((q + 4) * 16) ^ ((row & 7) << 4)));
    if (nb + row < NN) {
        float4* op = (float4*)(out + (size_t)(nb + row) * 32);
        op[q]     = o0;
        op[q + 4] = o1;
    }
}

// ===================== fallback: atomic edge kernel + scalar node =====
extern "C" __global__ void __launch_bounds__(256)
edge_msg_kernel(const float* __restrict__ pos, const float* __restrict__ vel,
                const int* __restrict__ ei,
                const float* __restrict__ w1, const float* __restrict__ b1,
                const float* __restrict__ w2, const float* __restrict__ b2,
                float* __restrict__ aggr)
{
    const int e = blockIdx.x * 256 + threadIdx.x;
    if (e >= NE) return;
    const int ns = ei[e];
    const int nd = ei[NE + e];
    float y[64];
#pragma unroll
    for (int j = 0; j < 64; ++j) y[j] = b1[j];
    for (int part = 0; part < 4; ++part) {
        const int    node  = (part < 2) ? nd : ns;
        const float* basep = (part & 1) ? vel : pos;
        const float4* xp = reinterpret_cast<const float4*>(basep + (size_t)node * 32);
        const float*  wp = w1 + part * 32 * 64;
        for (int q = 0; q < 8; ++q) {
            const float4 xv = xp[q];
#pragma unroll
            for (int kk = 0; kk < 4; ++kk) {
                const float xs = (kk == 0) ? xv.x : (kk == 1) ? xv.y
                               : (kk == 2) ? xv.z : xv.w;
                const float* wr = wp + (q * 4 + kk) * 64;
#pragma unroll
                for (int j = 0; j < 64; ++j) y[j] = fmaf(xs, wr[j], y[j]);
            }
        }
    }
    float mm[64];
#pragma unroll
    for (int c = 0; c < 64; ++c) mm[c] = b2[c];
#pragma unroll
    for (int j = 0; j < 64; ++j) {
        const float yj = fmaxf(y[j], 0.0f);
        const float* wr = w2 + j * 64;
#pragma unroll
        for (int c = 0; c < 64; ++c) mm[c] = fmaf(yj, wr[c], mm[c]);
    }
    float* ap = aggr + (size_t)nd * 64;
#pragma unroll
    for (int c = 0; c < 64; ++c) atomicAdd(ap + c, mm[c]);
}

extern "C" __global__ void __launch_bounds__(256)
node_upd_kernel(const float* __restrict__ pos, const float* __restrict__ vel,
                const float* __restrict__ aggr,
                const float* __restrict__ w1, const float* __restrict__ b1,
                const float* __restrict__ w2, const float* __restrict__ b2,
                const float* __restrict__ pw, const float* __restrict__ pb,
                float* __restrict__ out)
{
    const int v = blockIdx.x * 256 + threadIdx.x;
    if (v >= NN) return;

    float y[64];
#pragma unroll
    for (int j = 0; j < 64; ++j) y[j] = b1[j];
    for (int part = 0; part < 4; ++part) {
        const float* basep = (part == 0) ? pos + (size_t)v * 32
                           : (part == 1) ? vel + (size_t)v * 32
                           : aggr + (size_t)v * 64 + (size_t)(part - 2) * 32;
        const float4* xp = reinterpret_cast<const float4*>(basep);
        const float*  wp = w1 + part * 32 * 64;
        for (int q = 0; q < 8; ++q) {
            const float4 xv = xp[q];
#pragma unroll
            for (int kk = 0; kk < 4; ++kk) {
                const float xs = (kk == 0) ? xv.x : (kk == 1) ? xv.y
                               : (kk == 2) ? xv.z : xv.w;
                const float* wr = wp + (q * 4 + kk) * 64;
#pragma unroll
                for (int j = 0; j < 64; ++j) y[j] = fmaf(xs, wr[j], y[j]);
            }
        }
    }

    float u[64];
#pragma unroll
    for (int c = 0; c < 64; ++c) u[c] = b2[c];
#pragma unroll
    for (int j = 0; j < 64; ++j) {
        const float yj = fmaxf(y[j], 0.0f);
        const float* wr = w2 + j * 64;
#pragma unroll
        for (int c = 0; c < 64; ++c) u[c] = fmaf(yj, wr[c], u[c]);
    }

    float o[32];
#pragma unroll
    for (int c = 0; c < 32; ++c) o[c] = pb[c];
#pragma unroll
    for (int j = 0; j < 64; ++j) {
        const float* wr = pw + j * 32;
#pragma unroll
        for (int c = 0; c < 32; ++c) o[c] = fmaf(u[j], wr[c], o[c]);
    }

    float4* op = reinterpret_cast<float4*>(out + (size_t)v * 32);
#pragma unroll
    for (int q = 0; q < 8; ++q)
        op[q] = make_float4(o[q * 4], o[q * 4 + 1], o[q * 4 + 2], o[q * 4 + 3]);
}

// ===================== launcher =====================
extern "C" void kernel_launch(void* const* d_in, const int* in_sizes, int n_in,
                              void* d_out, int out_size, void* d_ws, size_t ws_size,
                              hipStream_t stream)
{
    const float* pos = (const float*)d_in[0];
    const float* vel = (const float*)d_in[1];
    const int*   ei  = (const int*)d_in[2];
    const float* mw1 = (const float*)d_in[3];
    const float* mb1 = (const float*)d_in[4];
    const float* mw2 = (const float*)d_in[5];
    const float* mb2 = (const float*)d_in[6];
    const float* uw1 = (const float*)d_in[7];
    const float* ub1 = (const float*)d_in[8];
    const float* uw2 = (const float*)d_in[9];
    const float* ub2 = (const float*)d_in[10];
    const float* pw  = (const float*)d_in[11];
    const float* pb  = (const float*)d_in[12];
    float* out = (float*)d_out;

    // workspace layout
    char* ws = (char*)d_ws;
    int* cnt  = (int*)ws;                 // NN
    int* gtot = cnt + NN;                 // 1 (+pad; memset covers cnt+gtot)
    int* base = gtot + 16;                // NN
    size_t off = ((size_t)(2 * NN + 64) * sizeof(int) + 255) & ~(size_t)255;

    _Float16* msg  = (_Float16*)(ws + off); off += (size_t)NE * 64 * 2;   // 204.8 MB
    _Float16* ag16 = (_Float16*)(ws + off); off += (size_t)NN * 64 * 2;   // 12.8 MB
    _Float16* hh   = (_Float16*)(ws + off); off += (size_t)NN * 64 * 2;   // 12.8 MB
    _Float16* mw1f = (_Float16*)(ws + off); off += 1024 * 8 * 2;          // 16 KB
    _Float16* mw2f = (_Float16*)(ws + off); off += 512 * 8 * 2;           // 8 KB
    _Float16* uw1f = (_Float16*)(ws + off); off += 1024 * 8 * 2;          // 16 KB
    _Float16* uw2f = (_Float16*)(ws + off); off += 512 * 8 * 2;           // 8 KB
    _Float16* pwf  = (_Float16*)(ws + off); off += 256 * 8 * 2;           // 4 KB
    int*      rank = (int*)(ws + off);      off += (size_t)NE * sizeof(int); // 6.4 MB
    const size_t need_full = off;

    if (ws_size >= need_full) {
        pack_w_kernel<<<13, 256, 0, stream>>>(mw1, mw2, uw1, uw2, pw,
                                              mw1f, mw2f, uw1f, uw2f, pwf);
        pack_h_kernel<<<NN * 8 / 256, 256, 0, stream>>>(pos, vel, hh);
        hipMemsetAsync(cnt, 0, (size_t)(NN + 16) * sizeof(int), stream);
        hist_kernel<<<(NE + 255) / 256, 256, 0, stream>>>(ei, cnt, rank);
        scanbase_kernel<<<NBLK, 256, 0, stream>>>(cnt, gtot, base);

        edge_mfma_kernel<<<NE / 256, 256, 0, stream>>>(
            hh, ei, mw1f, mw2f, mb1, mb2, base, rank, msg);
        agg_kernel<<<(NN + 3) / 4, 256, 0, stream>>>(msg, base, cnt, ag16);
        node_mfma_kernel<<<(NN + 63) / 64, 256, 0, stream>>>(
            hh, ag16, uw1f, uw2f, pwf, ub1, ub2, pb, out);
    } else {
        // fallback: atomic path (needs only 25.6 MB)
        float* aggr = (float*)d_ws;
        hipMemsetAsync(aggr, 0, (size_t)NN * 64 * sizeof(float), stream);
        edge_msg_kernel<<<NE / 256, 256, 0, stream>>>(pos, vel, ei,
                                                      mw1, mb1, mw2, mb2, aggr);
        node_upd_kernel<<<(NN + 255) / 256, 256, 0, stream>>>(
            pos, vel, aggr, uw1, ub1, uw2, ub2, pw, pb, out);
    }
}

// Round 6
// 225.502 us; speedup vs baseline: 25.2760x; 1.0370x over previous
//
#include <hip/hip_runtime.h>

#define NN 100000
#define NE 1600000
#define NBLK ((NN + 255) / 256)   // 391 scan blocks

typedef _Float16 f16x8 __attribute__((ext_vector_type(8)));
typedef float    f32x4 __attribute__((ext_vector_type(4)));

// ===================== prep kernel: zero aggr | pack h | hist | pack w ====
#define ZB   1563   // zero-aggr blocks (NN*16 float4 / 1024 per block)
#define PHB  3125   // pack_h blocks (NN*8 threads)
#define HIB  6250   // hist blocks (NE threads)
#define PWB  13     // pack_w blocks (3328 threads)

extern "C" __global__ void __launch_bounds__(256)
prep_kernel(const float* __restrict__ pos, const float* __restrict__ vel,
            const int* __restrict__ ei,
            const float* __restrict__ mw1, const float* __restrict__ mw2,
            const float* __restrict__ uw1, const float* __restrict__ uw2,
            const float* __restrict__ pw,
            _Float16* __restrict__ hh,
            _Float16* __restrict__ mw1f, _Float16* __restrict__ mw2f,
            _Float16* __restrict__ uw1f, _Float16* __restrict__ uw2f,
            _Float16* __restrict__ pwf,
            int* __restrict__ cnt, int* __restrict__ rank,
            float* __restrict__ aggr)
{
    const int b = blockIdx.x, tid = threadIdx.x;
    if (b < ZB) {                                      // zero aggr (25.6 MB)
        float4* p = (float4*)aggr;
        const int base4 = b * 1024 + tid;
        const float4 z = make_float4(0.f, 0.f, 0.f, 0.f);
#pragma unroll
        for (int k = 0; k < 4; ++k) {
            const int idx = base4 + k * 256;
            if (idx < NN * 16) p[idx] = z;
        }
    } else if (b < ZB + PHB) {                         // pack h -> fp16
        const int t = (b - ZB) * 256 + tid;
        const int node = t >> 3, seg = t & 7;
        const float* src = (seg < 4) ? pos + (size_t)node * 32 + seg * 8
                                     : vel + (size_t)node * 32 + (seg - 4) * 8;
        const float4 a = ((const float4*)src)[0];
        const float4 c = ((const float4*)src)[1];
        f16x8 r;
        r[0]=(_Float16)a.x; r[1]=(_Float16)a.y; r[2]=(_Float16)a.z; r[3]=(_Float16)a.w;
        r[4]=(_Float16)c.x; r[5]=(_Float16)c.y; r[6]=(_Float16)c.z; r[7]=(_Float16)c.w;
        *(f16x8*)(hh + (size_t)node * 64 + seg * 8) = r;
    } else if (b < ZB + PHB + HIB) {                   // histogram + rank
        const int e = (b - ZB - PHB) * 256 + tid;
        if (e < NE) rank[e] = atomicAdd(&cnt[ei[NE + e]], 1);
    } else {                                           // pack weights
        const int t2 = (b - ZB - PHB - HIB) * 256 + tid;
        if (t2 < 1024) {                               // msg_w1 [128,64]
            const int t = t2 >> 8, kk = (t2 >> 6) & 3, l = t2 & 63;
            f16x8 r;
#pragma unroll
            for (int j = 0; j < 8; ++j)
                r[j] = (_Float16)mw1[(kk * 32 + (l >> 4) * 8 + j) * 64 + t * 16 + (l & 15)];
            *(f16x8*)(mw1f + (size_t)t2 * 8) = r;
        } else if (t2 < 1536) {                        // msg_w2 [64,64]
            const int i = t2 - 1024;
            const int t = i >> 7, kk = (i >> 6) & 1, l = i & 63;
            f16x8 r;
#pragma unroll
            for (int j = 0; j < 8; ++j)
                r[j] = (_Float16)mw2[(kk * 32 + (l >> 4) * 8 + j) * 64 + t * 16 + (l & 15)];
            *(f16x8*)(mw2f + (size_t)i * 8) = r;
        } else if (t2 < 2560) {                        // upd_w1 [128,64]
            const int i = t2 - 1536;
            const int t = i >> 8, kk = (i >> 6) & 3, l = i & 63;
            f16x8 r;
#pragma unroll
            for (int j = 0; j < 8; ++j)
                r[j] = (_Float16)uw1[(kk * 32 + (l >> 4) * 8 + j) * 64 + t * 16 + (l & 15)];
            *(f16x8*)(uw1f + (size_t)i * 8) = r;
        } else if (t2 < 3072) {                        // upd_w2 [64,64]
            const int i = t2 - 2560;
            const int t = i >> 7, kk = (i >> 6) & 1, l = i & 63;
            f16x8 r;
#pragma unroll
            for (int j = 0; j < 8; ++j)
                r[j] = (_Float16)uw2[(kk * 32 + (l >> 4) * 8 + j) * 64 + t * 16 + (l & 15)];
            *(f16x8*)(uw2f + (size_t)i * 8) = r;
        } else if (t2 < 3328) {                        // pred_w [64,32]
            const int i = t2 - 3072;
            const int t = i >> 7, kk = (i >> 6) & 1, l = i & 63;
            f16x8 r;
#pragma unroll
            for (int j = 0; j < 8; ++j)
                r[j] = (_Float16)pw[(kk * 32 + (l >> 4) * 8 + j) * 32 + t * 16 + (l & 15)];
            *(f16x8*)(pwf + (size_t)i * 8) = r;
        }
    }
}

// ===================== scan: block prefix + one global atomic =============
extern "C" __global__ void __launch_bounds__(256)
scanbase_kernel(const int* __restrict__ cnt, int* __restrict__ gtot,
                int* __restrict__ base)
{
    __shared__ int s[256];
    __shared__ int boff;
    const int tid = threadIdx.x;
    const int i = blockIdx.x * 256 + tid;
    const int c = (i < NN) ? cnt[i] : 0;
    s[tid] = c;
    __syncthreads();
    for (int off = 1; off < 256; off <<= 1) {
        int v = (tid >= off) ? s[tid - off] : 0;
        __syncthreads();
        s[tid] += v;
        __syncthreads();
    }
    if (tid == 255) boff = atomicAdd(gtot, s[255]);
    __syncthreads();
    if (i < NN) base[i] = boff + s[tid] - c;
}

// ===================== scatter edges into dst-sorted slot order ===========
extern "C" __global__ void __launch_bounds__(256)
scatter_kernel(const int* __restrict__ ei, const int* __restrict__ rank,
               const int* __restrict__ base, int2* __restrict__ sd)
{
    const int e = blockIdx.x * 256 + threadIdx.x;
    if (e < NE) {
        const int s = ei[e], d = ei[NE + e];
        sd[base[d] + rank[e]] = make_int2(s, d);
    }
}

// ===================== fused edge MLP + segmented aggregation =============
// Block = 4 waves; wave owns 64 consecutive dst-sorted slots (4 tiles of 16).
// All 16 A-frag gathers issued up front. After each 16x64 fp16 M tile, each
// lane owns one feature column and segment-reduces over dst runs: interior
// runs -> plain store (exactly once), window-boundary runs -> atomicAdd.
extern "C" __global__ void __launch_bounds__(256)
edgeagg_kernel(const _Float16* __restrict__ hh,
               const int2* __restrict__ sd,
               const _Float16* __restrict__ w1f, const _Float16* __restrict__ w2f,
               const float* __restrict__ b1, const float* __restrict__ b2,
               float* __restrict__ aggr)
{
    __shared__ _Float16 sW1[4 * 4 * 64 * 8];   // 16 KB
    __shared__ _Float16 sW2[4 * 2 * 64 * 8];   // 8 KB
    __shared__ _Float16 sT[4][16 * 64];        // 8 KB (wave-private Y/M)

    const int tid = threadIdx.x;
    const int wave = tid >> 6, lane = tid & 63;
    const int m = lane & 15, g = lane >> 4;
    const int wslot = (blockIdx.x * 4 + wave) * 64;

    // coalesced slot metadata: one slot per lane
    const int2 sdv = sd[wslot + lane];

    // prefetch ALL 4 iterations' A-fragments (16 x 16B gathers, issued early)
    f16x8 A[4][4];
#pragma unroll
    for (int it = 0; it < 4; ++it) {
        const int ns = __shfl(sdv.x, it * 16 + m, 64);
        const int nd = __shfl(sdv.y, it * 16 + m, 64);
        const _Float16* hd = hh + (size_t)nd * 64 + g * 8;
        const _Float16* hs = hh + (size_t)ns * 64 + g * 8;
        A[it][0] = *(const f16x8*)(hd);
        A[it][1] = *(const f16x8*)(hd + 32);
        A[it][2] = *(const f16x8*)(hs);
        A[it][3] = *(const f16x8*)(hs + 32);
    }

    {   // stage W fragments (24 KB, block-shared)
        const uint4* g1 = (const uint4*)w1f; uint4* s1 = (uint4*)sW1;
#pragma unroll
        for (int i = 0; i < 4; ++i) s1[i * 256 + tid] = g1[i * 256 + tid];
        const uint4* g2 = (const uint4*)w2f; uint4* s2 = (uint4*)sW2;
#pragma unroll
        for (int i = 0; i < 2; ++i) s2[i * 256 + tid] = g2[i * 256 + tid];
    }

    const float bb1[4] = { b1[m], b1[16 + m], b1[32 + m], b1[48 + m] };
    const float bb2[4] = { b2[m], b2[16 + m], b2[32 + m], b2[48 + m] };

    __syncthreads();   // the only block barrier

    _Float16* Y = sT[wave];

    // segmented-reduction state (uniform across lanes)
    float racc = 0.0f;
    int   rnode = __shfl(sdv.y, 0, 64);
    int   firstRun = 1;

#pragma unroll
    for (int it = 0; it < 4; ++it) {
        // ---- layer 1: 16 MFMAs
        f32x4 acc[4] = {};
#pragma unroll
        for (int t = 0; t < 4; ++t) {
#pragma unroll
            for (int kk = 0; kk < 4; ++kk) {
                const f16x8 b = *(const f16x8*)(sW1 + ((t * 4 + kk) * 64 + lane) * 8);
                acc[t] = __builtin_amdgcn_mfma_f32_16x16x32_f16(A[it][kk], b, acc[t], 0, 0, 0);
            }
        }

        // ---- bias+relu -> fp16 -> swizzled wave-private Y tile
#pragma unroll
        for (int t = 0; t < 4; ++t) {
#pragma unroll
            for (int r = 0; r < 4; ++r) {
                const float y = fmaxf(acc[t][r] + bb1[t], 0.0f);
                const int row = g * 4 + r, col = t * 16 + m;
                const int byteoff = row * 128 + ((2 * col) ^ ((row & 7) << 4));
                *(_Float16*)((char*)Y + byteoff) = (_Float16)y;
            }
        }
        asm volatile("s_waitcnt lgkmcnt(0)" ::: "memory");
        __builtin_amdgcn_sched_barrier(0);

        // ---- layer 2 A-frags from swizzled Y
        f16x8 a2[2];
#pragma unroll
        for (int kk = 0; kk < 2; ++kk) {
            const int c = kk * 4 + g;
            a2[kk] = *(const f16x8*)((char*)Y + m * 128 + ((c * 16) ^ ((m & 7) << 4)));
        }
        asm volatile("s_waitcnt lgkmcnt(0)" ::: "memory");
        __builtin_amdgcn_sched_barrier(0);

        f32x4 acc2[4] = {};
#pragma unroll
        for (int kk = 0; kk < 2; ++kk) {
#pragma unroll
            for (int t = 0; t < 4; ++t) {
                const f16x8 b = *(const f16x8*)(sW2 + ((t * 2 + kk) * 64 + lane) * 8);
                acc2[t] = __builtin_amdgcn_mfma_f32_16x16x32_f16(a2[kk], b, acc2[t], 0, 0, 0);
            }
        }

        // ---- bias -> fp16 -> swizzled M tile (reuses Y buffer)
#pragma unroll
        for (int t = 0; t < 4; ++t) {
#pragma unroll
            for (int r = 0; r < 4; ++r) {
                const float mv = acc2[t][r] + bb2[t];
                const int row = g * 4 + r, col = t * 16 + m;
                const int byteoff = row * 128 + ((2 * col) ^ ((row & 7) << 4));
                *(_Float16*)((char*)Y + byteoff) = (_Float16)mv;
            }
        }
        asm volatile("s_waitcnt lgkmcnt(0)" ::: "memory");
        __builtin_amdgcn_sched_barrier(0);

        // ---- segmented column reduction: lane = feature, rows = sorted edges
#pragma unroll
        for (int r = 0; r < 16; ++r) {
            const int node = __shfl(sdv.y, it * 16 + r, 64);
            if (node != rnode) {
                float* ap = aggr + (size_t)rnode * 64 + lane;
                if (firstRun) atomicAdd(ap, racc);
                else          *ap = racc;
                firstRun = 0; racc = 0.0f; rnode = node;
            }
            const int byteoff = r * 128 + ((2 * lane) ^ ((r & 7) << 4));
            racc += (float)(*(const _Float16*)((const char*)Y + byteoff));
        }
        asm volatile("s_waitcnt lgkmcnt(0)" ::: "memory");
        __builtin_amdgcn_sched_barrier(0);
    }
    // final run touches the window end -> always atomic
    atomicAdd(aggr + (size_t)rnode * 64 + lane, racc);
}

// ===================== MFMA node kernel: h + fp32 aggr -> upd -> pred =====
extern "C" __global__ void __launch_bounds__(256)
node_mfma_kernel(const _Float16* __restrict__ hh, const float* __restrict__ aggr,
                 const _Float16* __restrict__ uw1f, const _Float16* __restrict__ uw2f,
                 const _Float16* __restrict__ pwf,
                 const float* __restrict__ b1, const float* __restrict__ b2,
                 const float* __restrict__ pb, float* __restrict__ out)
{
    __shared__ _Float16 sU1[4 * 4 * 64 * 8];   // 16 KB
    __shared__ _Float16 sU2[4 * 2 * 64 * 8];   // 8 KB
    __shared__ _Float16 sPW[2 * 2 * 64 * 8];   // 4 KB
    __shared__ _Float16 sT[4][16 * 64];        // 8 KB

    const int tid = threadIdx.x;
    {
        const uint4* g1 = (const uint4*)uw1f; uint4* s1 = (uint4*)sU1;
#pragma unroll
        for (int i = 0; i < 4; ++i) s1[i * 256 + tid] = g1[i * 256 + tid];
        const uint4* g2 = (const uint4*)uw2f; uint4* s2 = (uint4*)sU2;
#pragma unroll
        for (int i = 0; i < 2; ++i) s2[i * 256 + tid] = g2[i * 256 + tid];
        const uint4* g3 = (const uint4*)pwf;  uint4* s3 = (uint4*)sPW;
        s3[tid] = g3[tid];
    }
    __syncthreads();

    const int wave = tid >> 6, lane = tid & 63;
    const int m = lane & 15, g = lane >> 4;
    const int nb = (blockIdx.x * 4 + wave) * 16;
    const int v = nb + m;
    const int vl = (v < NN) ? v : (NN - 1);

    // A-fragments: x = [h(64) | aggr(64)] ; aggr is fp32 -> cvt
    const _Float16* hv = hh + (size_t)vl * 64 + g * 8;
    const f16x8 a0 = *(const f16x8*)(hv);
    const f16x8 a1 = *(const f16x8*)(hv + 32);
    const float* av = aggr + (size_t)vl * 64 + g * 8;
    const float4 x0 = *(const float4*)(av),      x1 = *(const float4*)(av + 4);
    const float4 y0 = *(const float4*)(av + 32), y1 = *(const float4*)(av + 36);
    f16x8 a2, a3;
    a2[0]=(_Float16)x0.x; a2[1]=(_Float16)x0.y; a2[2]=(_Float16)x0.z; a2[3]=(_Float16)x0.w;
    a2[4]=(_Float16)x1.x; a2[5]=(_Float16)x1.y; a2[6]=(_Float16)x1.z; a2[7]=(_Float16)x1.w;
    a3[0]=(_Float16)y0.x; a3[1]=(_Float16)y0.y; a3[2]=(_Float16)y0.z; a3[3]=(_Float16)y0.w;
    a3[4]=(_Float16)y1.x; a3[5]=(_Float16)y1.y; a3[6]=(_Float16)y1.z; a3[7]=(_Float16)y1.w;

    // layer 1
    f32x4 acc[4] = {};
#pragma unroll
    for (int t = 0; t < 4; ++t) {
        acc[t] = __builtin_amdgcn_mfma_f32_16x16x32_f16(
            a0, *(const f16x8*)(sU1 + ((t * 4 + 0) * 64 + lane) * 8), acc[t], 0, 0, 0);
        acc[t] = __builtin_amdgcn_mfma_f32_16x16x32_f16(
            a1, *(const f16x8*)(sU1 + ((t * 4 + 1) * 64 + lane) * 8), acc[t], 0, 0, 0);
        acc[t] = __builtin_amdgcn_mfma_f32_16x16x32_f16(
            a2, *(const f16x8*)(sU1 + ((t * 4 + 2) * 64 + lane) * 8), acc[t], 0, 0, 0);
        acc[t] = __builtin_amdgcn_mfma_f32_16x16x32_f16(
            a3, *(const f16x8*)(sU1 + ((t * 4 + 3) * 64 + lane) * 8), acc[t], 0, 0, 0);
    }

    _Float16* Y = sT[wave];
#pragma unroll
    for (int t = 0; t < 4; ++t) {
        const float bb = b1[t * 16 + m];
#pragma unroll
        for (int r = 0; r < 4; ++r) {
            const float y = fmaxf(acc[t][r] + bb, 0.0f);
            const int row = g * 4 + r, col = t * 16 + m;
            const int byteoff = row * 128 + ((2 * col) ^ ((row & 7) << 4));
            *(_Float16*)((char*)Y + byteoff) = (_Float16)y;
        }
    }
    asm volatile("s_waitcnt lgkmcnt(0)" ::: "memory");
    __builtin_amdgcn_sched_barrier(0);

    f16x8 ay[2];
#pragma unroll
    for (int kk = 0; kk < 2; ++kk) {
        const int c = kk * 4 + g;
        ay[kk] = *(const f16x8*)((char*)Y + m * 128 + ((c * 16) ^ ((m & 7) << 4)));
    }
    asm volatile("s_waitcnt lgkmcnt(0)" ::: "memory");
    __builtin_amdgcn_sched_barrier(0);

    // layer 2
    f32x4 acc2[4] = {};
#pragma unroll
    for (int kk = 0; kk < 2; ++kk) {
#pragma unroll
        for (int t = 0; t < 4; ++t) {
            const f16x8 b = *(const f16x8*)(sU2 + ((t * 2 + kk) * 64 + lane) * 8);
            acc2[t] = __builtin_amdgcn_mfma_f32_16x16x32_f16(ay[kk], b, acc2[t], 0, 0, 0);
        }
    }

    // u -> fp16 swizzled tile
#pragma unroll
    for (int t = 0; t < 4; ++t) {
        const float bb = b2[t * 16 + m];
#pragma unroll
        for (int r = 0; r < 4; ++r) {
            const float u = acc2[t][r] + bb;
            const int row = g * 4 + r, col = t * 16 + m;
            const int byteoff = row * 128 + ((2 * col) ^ ((row & 7) << 4));
            *(_Float16*)((char*)Y + byteoff) = (_Float16)u;
        }
    }
    asm volatile("s_waitcnt lgkmcnt(0)" ::: "memory");
    __builtin_amdgcn_sched_barrier(0);

    f16x8 au[2];
#pragma unroll
    for (int kk = 0; kk < 2; ++kk) {
        const int c = kk * 4 + g;
        au[kk] = *(const f16x8*)((char*)Y + m * 128 + ((c * 16) ^ ((m & 7) << 4)));
    }
    asm volatile("s_waitcnt lgkmcnt(0)" ::: "memory");
    __builtin_amdgcn_sched_barrier(0);

    // pred head: 64 -> 32
    f32x4 acc3[2] = {};
#pragma unroll
    for (int kk = 0; kk < 2; ++kk) {
#pragma unroll
        for (int t = 0; t < 2; ++t) {
            const f16x8 b = *(const f16x8*)(sPW + ((t * 2 + kk) * 64 + lane) * 8);
            acc3[t] = __builtin_amdgcn_mfma_f32_16x16x32_f16(au[kk], b, acc3[t], 0, 0, 0);
        }
    }

    // fp32 out tile (reuses sT as float[16][32], swizzled 16B chunks)
    float* F = (float*)Y;
#pragma unroll
    for (int t = 0; t < 2; ++t) {
        const float bb = pb[t * 16 + m];
#pragma unroll
        for (int r = 0; r < 4; ++r) {
            const int row = g * 4 + r, col = t * 16 + m;
            const int byteoff = row * 128 + ((4 * col) ^ ((row & 7) << 4));
            *(float*)((char*)F + byteoff) = acc3[t][r] + bb;
        }
    }
    asm volatile("s_waitcnt lgkmcnt(0)" ::: "memory");
    __builtin_amdgcn_sched_barrier(0);

    const int row = lane >> 2, q = lane & 3;
    const float4 o0 = *(const float4*)((char*)F + row * 128 + ((q * 16)       ^ ((row & 7) << 4)));
    const float4 o1 = *(const float4*)((char*)F + row * 128 + (((q + 4) * 16) ^ ((row & 7) << 4)));
    if (nb + row < NN) {
        float4* op = (float4*)(out + (size_t)(nb + row) * 32);
        op[q]     = o0;
        op[q + 4] = o1;
    }
}

// ===================== fallback: atomic edge kernel + scalar node =========
extern "C" __global__ void __launch_bounds__(256)
edge_msg_kernel(const float* __restrict__ pos, const float* __restrict__ vel,
                const int* __restrict__ ei,
                const float* __restrict__ w1, const float* __restrict__ b1,
                const float* __restrict__ w2, const float* __restrict__ b2,
                float* __restrict__ aggr)
{
    const int e = blockIdx.x * 256 + threadIdx.x;
    if (e >= NE) return;
    const int ns = ei[e];
    const int nd = ei[NE + e];
    float y[64];
#pragma unroll
    for (int j = 0; j < 64; ++j) y[j] = b1[j];
    for (int part = 0; part < 4; ++part) {
        const int    node  = (part < 2) ? nd : ns;
        const float* basep = (part & 1) ? vel : pos;
        const float4* xp = reinterpret_cast<const float4*>(basep + (size_t)node * 32);
        const float*  wp = w1 + part * 32 * 64;
        for (int q = 0; q < 8; ++q) {
            const float4 xv = xp[q];
#pragma unroll
            for (int kk = 0; kk < 4; ++kk) {
                const float xs = (kk == 0) ? xv.x : (kk == 1) ? xv.y
                               : (kk == 2) ? xv.z : xv.w;
                const float* wr = wp + (q * 4 + kk) * 64;
#pragma unroll
                for (int j = 0; j < 64; ++j) y[j] = fmaf(xs, wr[j], y[j]);
            }
        }
    }
    float mm[64];
#pragma unroll
    for (int c = 0; c < 64; ++c) mm[c] = b2[c];
#pragma unroll
    for (int j = 0; j < 64; ++j) {
        const float yj = fmaxf(y[j], 0.0f);
        const float* wr = w2 + j * 64;
#pragma unroll
        for (int c = 0; c < 64; ++c) mm[c] = fmaf(yj, wr[c], mm[c]);
    }
    float* ap = aggr + (size_t)nd * 64;
#pragma unroll
    for (int c = 0; c < 64; ++c) atomicAdd(ap + c, mm[c]);
}

extern "C" __global__ void __launch_bounds__(256)
node_upd_kernel(const float* __restrict__ pos, const float* __restrict__ vel,
                const float* __restrict__ aggr,
                const float* __restrict__ w1, const float* __restrict__ b1,
                const float* __restrict__ w2, const float* __restrict__ b2,
                const float* __restrict__ pw, const float* __restrict__ pb,
                float* __restrict__ out)
{
    const int v = blockIdx.x * 256 + threadIdx.x;
    if (v >= NN) return;

    float y[64];
#pragma unroll
    for (int j = 0; j < 64; ++j) y[j] = b1[j];
    for (int part = 0; part < 4; ++part) {
        const float* basep = (part == 0) ? pos + (size_t)v * 32
                           : (part == 1) ? vel + (size_t)v * 32
                           : aggr + (size_t)v * 64 + (size_t)(part - 2) * 32;
        const float4* xp = reinterpret_cast<const float4*>(basep);
        const float*  wp = w1 + part * 32 * 64;
        for (int q = 0; q < 8; ++q) {
            const float4 xv = xp[q];
#pragma unroll
            for (int kk = 0; kk < 4; ++kk) {
                const float xs = (kk == 0) ? xv.x : (kk == 1) ? xv.y
                               : (kk == 2) ? xv.z : xv.w;
                const float* wr = wp + (q * 4 + kk) * 64;
#pragma unroll
                for (int j = 0; j < 64; ++j) y[j] = fmaf(xs, wr[j], y[j]);
            }
        }
    }

    float u[64];
#pragma unroll
    for (int c = 0; c < 64; ++c) u[c] = b2[c];
#pragma unroll
    for (int j = 0; j < 64; ++j) {
        const float yj = fmaxf(y[j], 0.0f);
        const float* wr = w2 + j * 64;
#pragma unroll
        for (int c = 0; c < 64; ++c) u[c] = fmaf(yj, wr[c], u[c]);
    }

    float o[32];
#pragma unroll
    for (int c = 0; c < 32; ++c) o[c] = pb[c];
#pragma unroll
    for (int j = 0; j < 64; ++j) {
        const float* wr = pw + j * 32;
#pragma unroll
        for (int c = 0; c < 32; ++c) o[c] = fmaf(u[j], wr[c], o[c]);
    }

    float4* op = reinterpret_cast<float4*>(out + (size_t)v * 32);
#pragma unroll
    for (int q = 0; q < 8; ++q)
        op[q] = make_float4(o[q * 4], o[q * 4 + 1], o[q * 4 + 2], o[q * 4 + 3]);
}

// ===================== launcher ===========================================
extern "C" void kernel_launch(void* const* d_in, const int* in_sizes, int n_in,
                              void* d_out, int out_size, void* d_ws, size_t ws_size,
                              hipStream_t stream)
{
    const float* pos = (const float*)d_in[0];
    const float* vel = (const float*)d_in[1];
    const int*   ei  = (const int*)d_in[2];
    const float* mw1 = (const float*)d_in[3];
    const float* mb1 = (const float*)d_in[4];
    const float* mw2 = (const float*)d_in[5];
    const float* mb2 = (const float*)d_in[6];
    const float* uw1 = (const float*)d_in[7];
    const float* ub1 = (const float*)d_in[8];
    const float* uw2 = (const float*)d_in[9];
    const float* ub2 = (const float*)d_in[10];
    const float* pw  = (const float*)d_in[11];
    const float* pb  = (const float*)d_in[12];
    float* out = (float*)d_out;

    // workspace layout (~58.5 MB total)
    char* ws = (char*)d_ws;
    int* cnt  = (int*)ws;                 // NN
    int* gtot = cnt + NN;                 // 1 (+pad; memset covers cnt+gtot)
    int* base = gtot + 16;                // NN
    size_t off = ((size_t)(2 * NN + 64) * sizeof(int) + 255) & ~(size_t)255;

    int2*     sd   = (int2*)(ws + off);     off += (size_t)NE * 8;          // 12.8 MB
    int*      rank = (int*)(ws + off);      off += (size_t)NE * 4;          // 6.4 MB
    float*    aggr = (float*)(ws + off);    off += (size_t)NN * 64 * 4;     // 25.6 MB
    _Float16* hh   = (_Float16*)(ws + off); off += (size_t)NN * 64 * 2;     // 12.8 MB
    _Float16* mw1f = (_Float16*)(ws + off); off += 1024 * 8 * 2;            // 16 KB
    _Float16* mw2f = (_Float16*)(ws + off); off += 512 * 8 * 2;             // 8 KB
    _Float16* uw1f = (_Float16*)(ws + off); off += 1024 * 8 * 2;            // 16 KB
    _Float16* uw2f = (_Float16*)(ws + off); off += 512 * 8 * 2;             // 8 KB
    _Float16* pwf  = (_Float16*)(ws + off); off += 256 * 8 * 2;             // 4 KB
    const size_t need_full = off;

    if (ws_size >= need_full) {
        hipMemsetAsync(cnt, 0, (size_t)(NN + 16) * sizeof(int), stream);
        prep_kernel<<<ZB + PHB + HIB + PWB, 256, 0, stream>>>(
            pos, vel, ei, mw1, mw2, uw1, uw2, pw,
            hh, mw1f, mw2f, uw1f, uw2f, pwf, cnt, rank, aggr);
        scanbase_kernel<<<NBLK, 256, 0, stream>>>(cnt, gtot, base);
        scatter_kernel<<<(NE + 255) / 256, 256, 0, stream>>>(ei, rank, base, sd);
        edgeagg_kernel<<<NE / 256, 256, 0, stream>>>(
            hh, sd, mw1f, mw2f, mb1, mb2, aggr);
        node_mfma_kernel<<<(NN + 63) / 64, 256, 0, stream>>>(
            hh, aggr, uw1f, uw2f, pwf, ub1, ub2, pb, out);
    } else {
        // fallback: atomic path (needs only 25.6 MB)
        float* aggr2 = (float*)d_ws;
        hipMemsetAsync(aggr2, 0, (size_t)NN * 64 * sizeof(float), stream);
        edge_msg_kernel<<<NE / 256, 256, 0, stream>>>(pos, vel, ei,
                                                      mw1, mb1, mw2, mb2, aggr2);
        node_upd_kernel<<<(NN + 255) / 256, 256, 0, stream>>>(
            pos, vel, aggr2, uw1, ub1, uw2, ub2, pw, pb, out);
    }
}